// Round 1
// baseline (2460.524 us; speedup 1.0000x reference)
//
#include <hip/hip_runtime.h>
#include <hip/hip_bf16.h>
#include <math.h>

// xLSTM-Large forward: S=2048, D=1024, NH=4 (Dqk=128, Dv=256), UP=2752, L=2, V=32000.
// All activations f32 in workspace; big GEMMs run bf16 MFMA (f32 accum).
// Workspace requirement: 15,507,456 floats = ~62 MB.

#define S_LEN 2048
#define DMODEL 1024

typedef __attribute__((ext_vector_type(8))) __bf16 bf16x8;
typedef __attribute__((ext_vector_type(8))) unsigned short u16x8;
typedef __attribute__((ext_vector_type(4))) float f32x4v;

__device__ __forceinline__ unsigned short f2bf(float f) {
  unsigned int u = __float_as_uint(f);
  u += 0x7FFFu + ((u >> 16) & 1u);   // RNE
  return (unsigned short)(u >> 16);
}

// ---------------- embed ----------------
__global__ __launch_bounds__(256) void embed_kernel(
    const int* __restrict__ tok, const float* __restrict__ emb, float* __restrict__ x) {
  int s = blockIdx.x;
  int t = tok[s];
  const float4 v = *(const float4*)(emb + (size_t)t * DMODEL + threadIdx.x * 4);
  *(float4*)(x + (size_t)s * DMODEL + threadIdx.x * 4) = v;
}

// ---------------- rmsnorm (row = 1024) ----------------
__global__ __launch_bounds__(256) void rmsnorm_kernel(
    const float* __restrict__ x, const float* __restrict__ w, float* __restrict__ out) {
  int s = blockIdx.x, tid = threadIdx.x;
  const float* xr = x + (size_t)s * DMODEL;
  float4 v = *(const float4*)(xr + tid * 4);
  float ss = v.x * v.x + v.y * v.y + v.z * v.z + v.w * v.w;
#pragma unroll
  for (int off = 32; off > 0; off >>= 1) ss += __shfl_down(ss, off);
  __shared__ float red[4];
  if ((tid & 63) == 0) red[tid >> 6] = ss;
  __syncthreads();
  float tot = red[0] + red[1] + red[2] + red[3];
  float scale = rsqrtf(tot * (1.0f / DMODEL) + 1e-6f);
  float4 wv = *(const float4*)(w + tid * 4);
  float4 o;
  o.x = v.x * scale * wv.x; o.y = v.y * scale * wv.y;
  o.z = v.z * scale * wv.z; o.w = v.w * scale * wv.w;
  *(float4*)(out + (size_t)s * DMODEL + tid * 4) = o;
}

// ---------------- GEMM: C[M,N] = A[M,K] @ W[N,K]^T  (bf16 MFMA, f32 acc) ----------------
// EPI: 0 = store, 1 = C = acc + X (residual), 2 = softcap30(acc)
template <int EPI>
__global__ __launch_bounds__(256) void gemm_kernel(
    const float* __restrict__ A, const float* __restrict__ W,
    const float* __restrict__ X, float* __restrict__ C, int N, int K) {
  __shared__ unsigned short As[128 * 64];
  __shared__ unsigned short Bs[128 * 64];
  const int tid = threadIdx.x;
  const int bm = blockIdx.y * 128;
  const int bn = blockIdx.x * 128;
  const int wave = tid >> 6, lane = tid & 63;
  const int wr = (wave >> 1) * 64, wc = (wave & 1) * 64;
  const int lr = lane & 15, lhi = lane >> 4;
  f32x4v acc[4][4] = {};
  for (int k0 = 0; k0 < K; k0 += 64) {
#pragma unroll
    for (int i = 0; i < 4; ++i) {
      int gi = i * 256 + tid;          // 0..1023 : (row, 16B-group)
      int r = gi >> 3, cg = gi & 7;
      int col = ((cg ^ (r & 7)) << 3); // XOR swizzle (G4) to spread banks
      const float* srcA = A + (size_t)(bm + r) * K + k0 + cg * 8;
      float4 a0 = *(const float4*)srcA;
      float4 a1 = *(const float4*)(srcA + 4);
      u16x8 ua;
      ua[0] = f2bf(a0.x); ua[1] = f2bf(a0.y); ua[2] = f2bf(a0.z); ua[3] = f2bf(a0.w);
      ua[4] = f2bf(a1.x); ua[5] = f2bf(a1.y); ua[6] = f2bf(a1.z); ua[7] = f2bf(a1.w);
      *(u16x8*)&As[r * 64 + col] = ua;
      int rn = bn + r;
      float4 b0 = make_float4(0.f, 0.f, 0.f, 0.f), b1 = b0;
      if (rn < N) {
        const float* srcB = W + (size_t)rn * K + k0 + cg * 8;
        b0 = *(const float4*)srcB;
        b1 = *(const float4*)(srcB + 4);
      }
      u16x8 ub;
      ub[0] = f2bf(b0.x); ub[1] = f2bf(b0.y); ub[2] = f2bf(b0.z); ub[3] = f2bf(b0.w);
      ub[4] = f2bf(b1.x); ub[5] = f2bf(b1.y); ub[6] = f2bf(b1.z); ub[7] = f2bf(b1.w);
      *(u16x8*)&Bs[r * 64 + col] = ub;
    }
    __syncthreads();
#pragma unroll
    for (int kk = 0; kk < 2; ++kk) {
      bf16x8 af[4], bfr[4];
      const int gc = kk * 4 + lhi;
      const int colr = ((gc ^ (lr & 7)) << 3);
#pragma unroll
      for (int mi = 0; mi < 4; ++mi) {
        int row = wr + mi * 16 + lr;
        af[mi] = *(const bf16x8*)&As[row * 64 + colr];
      }
#pragma unroll
      for (int ni = 0; ni < 4; ++ni) {
        int row = wc + ni * 16 + lr;
        bfr[ni] = *(const bf16x8*)&Bs[row * 64 + colr];
      }
#pragma unroll
      for (int mi = 0; mi < 4; ++mi)
#pragma unroll
        for (int ni = 0; ni < 4; ++ni)
          acc[mi][ni] = __builtin_amdgcn_mfma_f32_16x16x32_bf16(af[mi], bfr[ni], acc[mi][ni], 0, 0, 0);
    }
    __syncthreads();
  }
#pragma unroll
  for (int mi = 0; mi < 4; ++mi) {
#pragma unroll
    for (int ni = 0; ni < 4; ++ni) {
#pragma unroll
      for (int j = 0; j < 4; ++j) {
        int row = bm + wr + mi * 16 + lhi * 4 + j;   // C/D layout (m89): row=(l>>4)*4+reg
        int col = bn + wc + ni * 16 + lr;            //                  col=l&15
        if (col < N) {
          float v = acc[mi][ni][j];
          if (EPI == 1) v += X[(size_t)row * N + col];
          if (EPI == 2) v = 30.0f * tanhf(v * (1.0f / 30.0f));
          C[(size_t)row * N + col] = v;
        }
      }
    }
  }
}

// ---------------- gate pre-activations: i/f = softcap15(xm @ Wi/Wf^T + b) ----------------
__global__ __launch_bounds__(256) void gates_kernel(
    const float* __restrict__ xm, const float* __restrict__ Wi, const float* __restrict__ bi,
    const float* __restrict__ Wf, const float* __restrict__ bfv,
    float* __restrict__ ipre, float* __restrict__ fpre) {
  int s = blockIdx.x;
  int head = threadIdx.x >> 6, lane = threadIdx.x & 63;
  const float* xr = xm + (size_t)s * DMODEL;
  const float* wi = Wi + head * DMODEL;
  const float* wf = Wf + head * DMODEL;
  float si = 0.f, sf = 0.f;
#pragma unroll
  for (int j = 0; j < 16; ++j) {
    float xv = xr[lane + j * 64];
    si += xv * wi[lane + j * 64];
    sf += xv * wf[lane + j * 64];
  }
#pragma unroll
  for (int off = 32; off > 0; off >>= 1) {
    si += __shfl_down(si, off);
    sf += __shfl_down(sf, off);
  }
  if (lane == 0) {
    ipre[head * S_LEN + s] = 15.0f * tanhf((si + bi[head]) * (1.0f / 15.0f));
    fpre[head * S_LEN + s] = 15.0f * tanhf((sf + bfv[head]) * (1.0f / 15.0f));
  }
}

// ---------------- per-head scan: F=cumsum(logsig(f)), g=i-F, M=cummax(g), e=exp(-(F+M)) ----------------
__global__ __launch_bounds__(256) void scan_kernel(
    const float* __restrict__ ipre, const float* __restrict__ fpre,
    float* __restrict__ garr, float* __restrict__ Marr, float* __restrict__ earr) {
  const int h = threadIdx.x >> 6;    // wave per head
  const int lane = threadIdx.x & 63; // lane owns 32 consecutive elements
  const int base = h * S_LEN + lane * 32;
  float lf[32];
  float lsum = 0.f;
#pragma unroll
  for (int e = 0; e < 32; ++e) {
    float f = fpre[base + e];
    float v = fminf(f, 0.f) - log1pf(expf(-fabsf(f)));  // stable log_sigmoid
    lf[e] = v;
    lsum += v;
  }
  float scan = lsum;
#pragma unroll
  for (int off = 1; off < 64; off <<= 1) {
    float t = __shfl_up(scan, off);
    if (lane >= off) scan += t;
  }
  float F0 = scan - lsum;  // exclusive prefix sum
  float gv[32];
  float F = F0, lmax = -1e30f;
#pragma unroll
  for (int e = 0; e < 32; ++e) {
    F += lf[e];
    float g = ipre[base + e] - F;
    gv[e] = g;
    lmax = fmaxf(lmax, g);
    garr[base + e] = g;
  }
  float ms = lmax;
#pragma unroll
  for (int off = 1; off < 64; off <<= 1) {
    float t = __shfl_up(ms, off);
    if (lane >= off) ms = fmaxf(ms, t);
  }
  float em = __shfl_up(ms, 1);
  if (lane == 0) em = -1e30f;  // exclusive prefix max
  float run = em;
  F = F0;
#pragma unroll
  for (int e = 0; e < 32; ++e) {
    F += lf[e];
    run = fmaxf(run, gv[e]);
    Marr[base + e] = run;
    earr[base + e] = expf(-(F + run));
  }
}

// ---------------- mLSTM parallel (f32, tiled 32t x 32s) ----------------
__global__ __launch_bounds__(256) void mlstm_kernel(
    const float* __restrict__ Q, const float* __restrict__ Kb,
    const float* __restrict__ V, const float* __restrict__ garr,
    const float* __restrict__ Marr, const float* __restrict__ earr,
    float* __restrict__ hout) {
  const int h = blockIdx.y;
  const int t0 = blockIdx.x * 32;
  const int tid = threadIdx.x;
  __shared__ float Qs[32][129];
  __shared__ float Ks[32][129];
  __shared__ float Vs[32][260];
  __shared__ float Cs[32][33];
  __shared__ float csum[32];
#pragma unroll
  for (int i = 0; i < 4; ++i) {  // stage Q tile 32x128
    int flat = (i * 256 + tid) * 4;
    int r = flat >> 7, c = flat & 127;
    float4 qv = *(const float4*)(Q + (size_t)(t0 + r) * 512 + h * 128 + c);
    Qs[r][c] = qv.x; Qs[r][c + 1] = qv.y; Qs[r][c + 2] = qv.z; Qs[r][c + 3] = qv.w;
  }
  if (tid < 32) csum[tid] = 0.f;
  const int ts = tid & 31;  // score phase: t index
  const int sg = tid >> 5;  // score phase: s-group (8 groups of 4)
  const int tp = tid >> 3;  // PV phase: t index
  const int dg = tid & 7;   // PV phase: dv group
  const float Mt = Marr[h * S_LEN + t0 + ts];
  const float rs = 0.08838834764831845f;  // 1/sqrt(128)
  float4 hacc[8];
#pragma unroll
  for (int i = 0; i < 8; ++i) hacc[i] = make_float4(0.f, 0.f, 0.f, 0.f);
  const int nchunk = blockIdx.x + 1;
  for (int ch = 0; ch < nchunk; ++ch) {
    const int s0 = ch * 32;
    __syncthreads();  // prev PV done before restaging
#pragma unroll
    for (int i = 0; i < 4; ++i) {  // stage K tile 32x128
      int flat = (i * 256 + tid) * 4;
      int r = flat >> 7, c = flat & 127;
      float4 kv = *(const float4*)(Kb + (size_t)(s0 + r) * 512 + h * 128 + c);
      Ks[r][c] = kv.x; Ks[r][c + 1] = kv.y; Ks[r][c + 2] = kv.z; Ks[r][c + 3] = kv.w;
    }
#pragma unroll
    for (int i = 0; i < 8; ++i) {  // stage V tile 32x256
      int flat = (i * 256 + tid) * 4;
      int r = flat >> 8, c = flat & 255;
      float4 vv = *(const float4*)(V + (size_t)(s0 + r) * 1024 + h * 256 + c);
      *(float4*)&Vs[r][c] = vv;
    }
    __syncthreads();
    float sc0 = 0.f, sc1 = 0.f, sc2 = 0.f, sc3 = 0.f;
    for (int d = 0; d < 128; ++d) {
      float qv = Qs[ts][d];
      sc0 += qv * Ks[sg * 4 + 0][d];
      sc1 += qv * Ks[sg * 4 + 1][d];
      sc2 += qv * Ks[sg * 4 + 2][d];
      sc3 += qv * Ks[sg * 4 + 3][d];
    }
    float part = 0.f;
#pragma unroll
    for (int j = 0; j < 4; ++j) {
      int sglob = s0 + sg * 4 + j;
      float wgt = 0.f;
      if (sglob <= t0 + ts) wgt = expf(garr[h * S_LEN + sglob] - Mt);
      float scv = (j == 0) ? sc0 : (j == 1) ? sc1 : (j == 2) ? sc2 : sc3;
      float cv = scv * rs * wgt;
      Cs[ts][sg * 4 + j] = cv;
      part += cv;
    }
    atomicAdd(&csum[ts], part);
    __syncthreads();  // Cs complete before PV
    for (int j = 0; j < 32; ++j) {
      float cv = Cs[tp][j];
#pragma unroll
      for (int qy = 0; qy < 8; ++qy) {
        float4 vv = *(const float4*)&Vs[j][qy * 32 + dg * 4];
        hacc[qy].x += cv * vv.x; hacc[qy].y += cv * vv.y;
        hacc[qy].z += cv * vv.z; hacc[qy].w += cv * vv.w;
      }
    }
  }
  __syncthreads();
  float nv = fmaxf(fabsf(csum[tp]), earr[h * S_LEN + t0 + tp]);
  float inv = 1.0f / (nv + 1e-6f);
#pragma unroll
  for (int qy = 0; qy < 8; ++qy) {
    float4 o;
    o.x = hacc[qy].x * inv; o.y = hacc[qy].y * inv;
    o.z = hacc[qy].z * inv; o.w = hacc[qy].w * inv;
    *(float4*)(hout + (size_t)(t0 + tp) * DMODEL + h * 256 + qy * 32 + dg * 4) = o;
  }
}

// ---------------- multihead LayerNorm (DH=256) + out-gate ----------------
__global__ __launch_bounds__(256) void mhln_gate_kernel(
    const float* __restrict__ hout, const float* __restrict__ og,
    const float* __restrict__ mhw, float* __restrict__ gact) {
  int s = blockIdx.x;
  int head = threadIdx.x >> 6, lane = threadIdx.x & 63;
  const float* hr = hout + (size_t)s * DMODEL + head * 256;
  float v0 = hr[lane], v1 = hr[lane + 64], v2 = hr[lane + 128], v3 = hr[lane + 192];
  float sum = v0 + v1 + v2 + v3;
#pragma unroll
  for (int off = 32; off > 0; off >>= 1) sum += __shfl_xor(sum, off);
  float mu = sum * (1.0f / 256.0f);
  float d0 = v0 - mu, d1 = v1 - mu, d2 = v2 - mu, d3 = v3 - mu;
  float vs = d0 * d0 + d1 * d1 + d2 * d2 + d3 * d3;
#pragma unroll
  for (int off = 32; off > 0; off >>= 1) vs += __shfl_xor(vs, off);
  float rstd = rsqrtf(vs * (1.0f / 256.0f) + 1e-6f);
  float dn[4] = {d0, d1, d2, d3};
#pragma unroll
  for (int qy = 0; qy < 4; ++qy) {
    int c = head * 256 + qy * 64 + lane;
    float ov = og[(size_t)s * DMODEL + c];
    float sig = 1.0f / (1.0f + expf(-ov));
    gact[(size_t)s * DMODEL + c] = dn[qy] * rstd * mhw[c] * sig;
  }
}

// ---------------- FFN act: G = silu(G) * U ----------------
__global__ __launch_bounds__(256) void silu_mul_kernel(
    float* __restrict__ G, const float* __restrict__ U) {
  size_t i = ((size_t)blockIdx.x * 256 + threadIdx.x) * 4;
  float4 gv = *(const float4*)(G + i);
  float4 uv = *(const float4*)(U + i);
  float4 o;
  o.x = gv.x / (1.f + expf(-gv.x)) * uv.x;
  o.y = gv.y / (1.f + expf(-gv.y)) * uv.y;
  o.z = gv.z / (1.f + expf(-gv.z)) * uv.z;
  o.w = gv.w / (1.f + expf(-gv.w)) * uv.w;
  *(float4*)(G + i) = o;
}

extern "C" void kernel_launch(void* const* d_in, const int* in_sizes, int n_in,
                              void* d_out, int out_size, void* d_ws, size_t ws_size,
                              hipStream_t stream) {
  (void)in_sizes; (void)n_in; (void)out_size; (void)ws_size;
  const int*   tok   = (const int*)d_in[0];
  const float* emb   = (const float*)d_in[1];
  const float* norm1 = (const float*)d_in[2];
  const float* Wq    = (const float*)d_in[3];
  const float* Wk    = (const float*)d_in[4];
  const float* Wv    = (const float*)d_in[5];
  const float* Wog   = (const float*)d_in[6];
  const float* Wi    = (const float*)d_in[7];
  const float* bi    = (const float*)d_in[8];
  const float* Wf    = (const float*)d_in[9];
  const float* bfp   = (const float*)d_in[10];
  const float* mhw   = (const float*)d_in[11];
  const float* Wout  = (const float*)d_in[12];
  const float* norm2 = (const float*)d_in[13];
  const float* Wg    = (const float*)d_in[14];
  const float* Wu    = (const float*)d_in[15];
  const float* Wd    = (const float*)d_in[16];
  const float* onw   = (const float*)d_in[17];
  const float* Wlm   = (const float*)d_in[18];

  float* ws = (float*)d_ws;
  const size_t M2 = 2097152;  // 2048*1024
  float* x    = ws;
  float* xm   = ws + M2;
  float* q    = ws + 2 * M2;
  float* kbuf = ws + 2 * M2 + 1048576;
  float* v    = ws + 3 * M2;
  float* og   = ws + 4 * M2;
  float* hout = ws + 5 * M2;
  float* gact = ws + 6 * M2;
  // FFN overlays (q..gact region dead during FFN):
  float* Gbuf = ws + 2 * M2;
  float* Ubuf = Gbuf + (size_t)2048 * 2752;
  float* ipre = Ubuf + (size_t)2048 * 2752;
  float* fpre = ipre + 8192;
  float* garr = fpre + 8192;
  float* Marr = garr + 8192;
  float* earr = Marr + 8192;

  embed_kernel<<<2048, 256, 0, stream>>>(tok, emb, x);

  for (int l = 0; l < 2; ++l) {
    const float* n1   = norm1 + (size_t)l * 1024;
    const float* wq   = Wq   + (size_t)l * 512 * 1024;
    const float* wk   = Wk   + (size_t)l * 512 * 1024;
    const float* wv   = Wv   + (size_t)l * 1024 * 1024;
    const float* wog  = Wog  + (size_t)l * 1024 * 1024;
    const float* wi   = Wi   + (size_t)l * 4 * 1024;
    const float* bil  = bi   + (size_t)l * 4;
    const float* wf   = Wf   + (size_t)l * 4 * 1024;
    const float* bfl  = bfp  + (size_t)l * 4;
    const float* mhwl = mhw  + (size_t)l * 1024;
    const float* wout = Wout + (size_t)l * 1024 * 1024;
    const float* n2   = norm2 + (size_t)l * 1024;
    const float* wg   = Wg   + (size_t)l * 2752 * 1024;
    const float* wu   = Wu   + (size_t)l * 2752 * 1024;
    const float* wd   = Wd   + (size_t)l * 1024 * 2752;

    rmsnorm_kernel<<<2048, 256, 0, stream>>>(x, n1, xm);
    gemm_kernel<0><<<dim3(4, 16), 256, 0, stream>>>(xm, wq, nullptr, q, 512, 1024);
    gemm_kernel<0><<<dim3(4, 16), 256, 0, stream>>>(xm, wk, nullptr, kbuf, 512, 1024);
    gemm_kernel<0><<<dim3(8, 16), 256, 0, stream>>>(xm, wv, nullptr, v, 1024, 1024);
    gemm_kernel<0><<<dim3(8, 16), 256, 0, stream>>>(xm, wog, nullptr, og, 1024, 1024);
    gates_kernel<<<2048, 256, 0, stream>>>(xm, wi, bil, wf, bfl, ipre, fpre);
    scan_kernel<<<1, 256, 0, stream>>>(ipre, fpre, garr, Marr, earr);
    mlstm_kernel<<<dim3(64, 4), 256, 0, stream>>>(q, kbuf, v, garr, Marr, earr, hout);
    mhln_gate_kernel<<<2048, 256, 0, stream>>>(hout, og, mhwl, gact);
    gemm_kernel<1><<<dim3(8, 16), 256, 0, stream>>>(gact, wout, x, x, 1024, 1024);
    rmsnorm_kernel<<<2048, 256, 0, stream>>>(x, n2, xm);
    gemm_kernel<0><<<dim3(22, 16), 256, 0, stream>>>(xm, wg, nullptr, Gbuf, 2752, 1024);
    gemm_kernel<0><<<dim3(22, 16), 256, 0, stream>>>(xm, wu, nullptr, Ubuf, 2752, 1024);
    silu_mul_kernel<<<5504, 256, 0, stream>>>(Gbuf, Ubuf);
    gemm_kernel<1><<<dim3(8, 16), 256, 0, stream>>>(Gbuf, wd, x, x, 1024, 2752);
  }

  rmsnorm_kernel<<<2048, 256, 0, stream>>>(x, onw, xm);
  gemm_kernel<2><<<dim3(250, 16), 256, 0, stream>>>(xm, Wlm, nullptr, (float*)d_out, 32000, 1024);
}

// Round 2
// 2098.566 us; speedup vs baseline: 1.1725x; 1.1725x over previous
//
#include <hip/hip_runtime.h>
#include <hip/hip_bf16.h>
#include <math.h>

// xLSTM-Large forward: S=2048, D=1024, NH=4 (Dqk=128, Dv=256), UP=2752, L=2, V=32000.
// All activations f32 in workspace; big GEMMs + mLSTM run bf16 MFMA (f32 accum).
// Workspace requirement: 15,507,456 floats = ~62 MB.

#define S_LEN 2048
#define DMODEL 1024

typedef __attribute__((ext_vector_type(8))) __bf16 bf16x8;
typedef __attribute__((ext_vector_type(8))) unsigned short u16x8;
typedef __attribute__((ext_vector_type(4))) unsigned short u16x4;
typedef __attribute__((ext_vector_type(4))) float f32x4v;

union cvu { u16x8 u; bf16x8 b; };

__device__ __forceinline__ unsigned short f2bf(float f) {
  unsigned int u = __float_as_uint(f);
  u += 0x7FFFu + ((u >> 16) & 1u);   // RNE
  return (unsigned short)(u >> 16);
}

__device__ __forceinline__ bf16x8 ld_bf8(const unsigned short* p, int byte_off) {
  cvu c;
  c.u = *(const u16x8*)((const char*)p + byte_off);
  return c.b;
}

// ---------------- embed ----------------
__global__ __launch_bounds__(256) void embed_kernel(
    const int* __restrict__ tok, const float* __restrict__ emb, float* __restrict__ x) {
  int s = blockIdx.x;
  int t = tok[s];
  const float4 v = *(const float4*)(emb + (size_t)t * DMODEL + threadIdx.x * 4);
  *(float4*)(x + (size_t)s * DMODEL + threadIdx.x * 4) = v;
}

// ---------------- rmsnorm (row = 1024) ----------------
__global__ __launch_bounds__(256) void rmsnorm_kernel(
    const float* __restrict__ x, const float* __restrict__ w, float* __restrict__ out) {
  int s = blockIdx.x, tid = threadIdx.x;
  const float* xr = x + (size_t)s * DMODEL;
  float4 v = *(const float4*)(xr + tid * 4);
  float ss = v.x * v.x + v.y * v.y + v.z * v.z + v.w * v.w;
#pragma unroll
  for (int off = 32; off > 0; off >>= 1) ss += __shfl_down(ss, off);
  __shared__ float red[4];
  if ((tid & 63) == 0) red[tid >> 6] = ss;
  __syncthreads();
  float tot = red[0] + red[1] + red[2] + red[3];
  float scale = rsqrtf(tot * (1.0f / DMODEL) + 1e-6f);
  float4 wv = *(const float4*)(w + tid * 4);
  float4 o;
  o.x = v.x * scale * wv.x; o.y = v.y * scale * wv.y;
  o.z = v.z * scale * wv.z; o.w = v.w * scale * wv.w;
  *(float4*)(out + (size_t)s * DMODEL + tid * 4) = o;
}

// ---------------- GEMM: C[M,N] = A[M,K] @ W[N,K]^T  (bf16 MFMA, f32 acc) ----------------
// EPI: 0 = store, 1 = C = acc + X (residual), 2 = softcap30(acc), 3 = store transposed C[N][M]
template <int EPI>
__global__ __launch_bounds__(256) void gemm_kernel(
    const float* __restrict__ A, const float* __restrict__ W,
    const float* __restrict__ X, float* __restrict__ C, int N, int K) {
  __shared__ unsigned short As[128 * 64];
  __shared__ unsigned short Bs[128 * 64];
  const int tid = threadIdx.x;
  const int bm = blockIdx.y * 128;
  const int bn = blockIdx.x * 128;
  const int wave = tid >> 6, lane = tid & 63;
  const int wr = (wave >> 1) * 64, wc = (wave & 1) * 64;
  const int lr = lane & 15, lhi = lane >> 4;
  f32x4v acc[4][4] = {};
  for (int k0 = 0; k0 < K; k0 += 64) {
#pragma unroll
    for (int i = 0; i < 4; ++i) {
      int gi = i * 256 + tid;          // 0..1023 : (row, 16B-group)
      int r = gi >> 3, cg = gi & 7;
      int col = ((cg ^ (r & 7)) << 3); // XOR swizzle (G4) to spread banks
      const float* srcA = A + (size_t)(bm + r) * K + k0 + cg * 8;
      float4 a0 = *(const float4*)srcA;
      float4 a1 = *(const float4*)(srcA + 4);
      u16x8 ua;
      ua[0] = f2bf(a0.x); ua[1] = f2bf(a0.y); ua[2] = f2bf(a0.z); ua[3] = f2bf(a0.w);
      ua[4] = f2bf(a1.x); ua[5] = f2bf(a1.y); ua[6] = f2bf(a1.z); ua[7] = f2bf(a1.w);
      *(u16x8*)&As[r * 64 + col] = ua;
      int rn = bn + r;
      float4 b0 = make_float4(0.f, 0.f, 0.f, 0.f), b1 = b0;
      if (rn < N) {
        const float* srcB = W + (size_t)rn * K + k0 + cg * 8;
        b0 = *(const float4*)srcB;
        b1 = *(const float4*)(srcB + 4);
      }
      u16x8 ub;
      ub[0] = f2bf(b0.x); ub[1] = f2bf(b0.y); ub[2] = f2bf(b0.z); ub[3] = f2bf(b0.w);
      ub[4] = f2bf(b1.x); ub[5] = f2bf(b1.y); ub[6] = f2bf(b1.z); ub[7] = f2bf(b1.w);
      *(u16x8*)&Bs[r * 64 + col] = ub;
    }
    __syncthreads();
#pragma unroll
    for (int kk = 0; kk < 2; ++kk) {
      bf16x8 af[4], bfr[4];
      const int gc = kk * 4 + lhi;
      const int colr = ((gc ^ (lr & 7)) << 3);
#pragma unroll
      for (int mi = 0; mi < 4; ++mi) {
        int row = wr + mi * 16 + lr;
        af[mi] = *(const bf16x8*)&As[row * 64 + colr];
      }
#pragma unroll
      for (int ni = 0; ni < 4; ++ni) {
        int row = wc + ni * 16 + lr;
        bfr[ni] = *(const bf16x8*)&Bs[row * 64 + colr];
      }
#pragma unroll
      for (int mi = 0; mi < 4; ++mi)
#pragma unroll
        for (int ni = 0; ni < 4; ++ni)
          acc[mi][ni] = __builtin_amdgcn_mfma_f32_16x16x32_bf16(af[mi], bfr[ni], acc[mi][ni], 0, 0, 0);
    }
    __syncthreads();
  }
#pragma unroll
  for (int mi = 0; mi < 4; ++mi) {
#pragma unroll
    for (int ni = 0; ni < 4; ++ni) {
#pragma unroll
      for (int j = 0; j < 4; ++j) {
        int row = bm + wr + mi * 16 + lhi * 4 + j;   // C/D layout (m89): row=(l>>4)*4+reg
        int col = bn + wc + ni * 16 + lr;            //                  col=l&15
        if (col < N) {
          float v = acc[mi][ni][j];
          if (EPI == 1) v += X[(size_t)row * N + col];
          if (EPI == 2) v = 30.0f * tanhf(v * (1.0f / 30.0f));
          if (EPI == 3) C[(size_t)col * S_LEN + row] = v;
          else          C[(size_t)row * N + col] = v;
        }
      }
    }
  }
}

// ---------------- gate pre-activations: i/f = softcap15(xm @ Wi/Wf^T + b) ----------------
__global__ __launch_bounds__(256) void gates_kernel(
    const float* __restrict__ xm, const float* __restrict__ Wi, const float* __restrict__ bi,
    const float* __restrict__ Wf, const float* __restrict__ bfv,
    float* __restrict__ ipre, float* __restrict__ fpre) {
  int s = blockIdx.x;
  int head = threadIdx.x >> 6, lane = threadIdx.x & 63;
  const float* xr = xm + (size_t)s * DMODEL;
  const float* wi = Wi + head * DMODEL;
  const float* wf = Wf + head * DMODEL;
  float si = 0.f, sf = 0.f;
#pragma unroll
  for (int j = 0; j < 16; ++j) {
    float xv = xr[lane + j * 64];
    si += xv * wi[lane + j * 64];
    sf += xv * wf[lane + j * 64];
  }
#pragma unroll
  for (int off = 32; off > 0; off >>= 1) {
    si += __shfl_down(si, off);
    sf += __shfl_down(sf, off);
  }
  if (lane == 0) {
    ipre[head * S_LEN + s] = 15.0f * tanhf((si + bi[head]) * (1.0f / 15.0f));
    fpre[head * S_LEN + s] = 15.0f * tanhf((sf + bfv[head]) * (1.0f / 15.0f));
  }
}

// ---------------- per-head scan: F=cumsum(logsig(f)), g=i-F, M=cummax(g), e=exp(-(F+M)) ----------------
__global__ __launch_bounds__(256) void scan_kernel(
    const float* __restrict__ ipre, const float* __restrict__ fpre,
    float* __restrict__ garr, float* __restrict__ Marr, float* __restrict__ earr) {
  const int h = threadIdx.x >> 6;    // wave per head
  const int lane = threadIdx.x & 63; // lane owns 32 consecutive elements
  const int base = h * S_LEN + lane * 32;
  float lf[32];
  float lsum = 0.f;
#pragma unroll
  for (int e = 0; e < 32; ++e) {
    float f = fpre[base + e];
    float v = fminf(f, 0.f) - log1pf(expf(-fabsf(f)));  // stable log_sigmoid
    lf[e] = v;
    lsum += v;
  }
  float scan = lsum;
#pragma unroll
  for (int off = 1; off < 64; off <<= 1) {
    float t = __shfl_up(scan, off);
    if (lane >= off) scan += t;
  }
  float F0 = scan - lsum;  // exclusive prefix sum
  float gv[32];
  float F = F0, lmax = -1e30f;
#pragma unroll
  for (int e = 0; e < 32; ++e) {
    F += lf[e];
    float g = ipre[base + e] - F;
    gv[e] = g;
    lmax = fmaxf(lmax, g);
    garr[base + e] = g;
  }
  float ms = lmax;
#pragma unroll
  for (int off = 1; off < 64; off <<= 1) {
    float t = __shfl_up(ms, off);
    if (lane >= off) ms = fmaxf(ms, t);
  }
  float em = __shfl_up(ms, 1);
  if (lane == 0) em = -1e30f;  // exclusive prefix max
  float run = em;
  F = F0;
#pragma unroll
  for (int e = 0; e < 32; ++e) {
    F += lf[e];
    run = fmaxf(run, gv[e]);
    Marr[base + e] = run;
    earr[base + e] = expf(-(F + run));
  }
}

// ---------------- mLSTM parallel, bf16 MFMA flash-style ----------------
// Grid: (32 t-tiles of 64, 4 heads). Block: 256 = 4 waves, wave w owns t rows [T*64+w*16, +16).
// Per s-chunk of 64: stage K[64][128] + Vt[256][64] (XOR-swizzled bf16 LDS),
// scores = mfma(Q,K^T), weight exp(g[s]-M[t]) + causal mask in f32, row-sum n,
// P->bf16 via swizzled LDS, h += mfma(P, Vt^T). Epilogue: / (max(|n|, e^-m) + eps).
__global__ __launch_bounds__(256) void mlstm_mfma_kernel(
    const float* __restrict__ Q, const float* __restrict__ Kb,
    const float* __restrict__ vT, const float* __restrict__ garr,
    const float* __restrict__ Marr, const float* __restrict__ earr,
    float* __restrict__ hout) {
  const int h = blockIdx.y;
  const int T = blockIdx.x;
  const int tid = threadIdx.x;
  const int w = tid >> 6, l = tid & 63;
  const int lr = l & 15, lg = l >> 4;
  const int hbase = h * S_LEN;
  const int sr = tid >> 4;   // staging: 16 rows per pass
  const int sc = tid & 15;   // staging: 16 col-groups

  __shared__ unsigned short Ks[64 * 128];   // [s][d] swizzled, 16 KB
  __shared__ unsigned short Vs[256 * 64];   // [dv][s] swizzled, 32 KB
  __shared__ unsigned short Ps[64 * 64];    // [t][s] swizzled, 8 KB

  // Q A-fragments: lane holds Q[t = base + lr][d = kt*32 + lg*8 .. +8]
  bf16x8 qf[4];
  {
    const float* qrow = Q + (size_t)(T * 64 + w * 16 + lr) * 512 + h * 128 + lg * 8;
#pragma unroll
    for (int kt = 0; kt < 4; ++kt) {
      float4 a0 = *(const float4*)(qrow + kt * 32);
      float4 a1 = *(const float4*)(qrow + kt * 32 + 4);
      cvu c;
      c.u[0] = f2bf(a0.x); c.u[1] = f2bf(a0.y); c.u[2] = f2bf(a0.z); c.u[3] = f2bf(a0.w);
      c.u[4] = f2bf(a1.x); c.u[5] = f2bf(a1.y); c.u[6] = f2bf(a1.z); c.u[7] = f2bf(a1.w);
      qf[kt] = c.b;
    }
  }
  float Mt[4];
#pragma unroll
  for (int j = 0; j < 4; ++j) Mt[j] = Marr[hbase + T * 64 + w * 16 + lg * 4 + j];

  f32x4v pv[16] = {};
  float nacc[4] = {0.f, 0.f, 0.f, 0.f};
  const float rs = 0.08838834764831845f;  // 1/sqrt(128)

  for (int ch = 0; ch <= T; ++ch) {
    const int s0 = ch * 64;
    __syncthreads();  // previous chunk's LDS reads done
    // ---- stage K chunk: rows s0..s0+63, 128 d ----
#pragma unroll
    for (int i = 0; i < 4; ++i) {
      int r = i * 16 + sr;
      int c = sc * 8;
      const float* src = Kb + (size_t)(s0 + r) * 512 + h * 128 + c;
      float4 a0 = *(const float4*)src;
      float4 a1 = *(const float4*)(src + 4);
      u16x8 u;
      u[0] = f2bf(a0.x); u[1] = f2bf(a0.y); u[2] = f2bf(a0.z); u[3] = f2bf(a0.w);
      u[4] = f2bf(a1.x); u[5] = f2bf(a1.y); u[6] = f2bf(a1.z); u[7] = f2bf(a1.w);
      int byte = r * 256 + ((c * 2) ^ ((r & 7) << 4));
      *(u16x8*)((char*)Ks + byte) = u;
    }
    // ---- stage V^T chunk: rows dv 0..255 (head dv), cols s0..s0+63 ----
#pragma unroll
    for (int i = 0; i < 16; ++i) {
      int r = i * 16 + sr;
      float4 a0 = *(const float4*)(vT + (size_t)(h * 256 + r) * S_LEN + s0 + sc * 4);
      u16x4 u;
      u[0] = f2bf(a0.x); u[1] = f2bf(a0.y); u[2] = f2bf(a0.z); u[3] = f2bf(a0.w);
      int byte = r * 128 + ((sc * 8) ^ ((r & 7) << 4));
      *(u16x4*)((char*)Vs + byte) = u;
    }
    __syncthreads();
    // ---- scores: S[t][s] tile 16x64 per wave ----
    f32x4v sa[4] = {};
#pragma unroll
    for (int ni = 0; ni < 4; ++ni) {
#pragma unroll
      for (int kt = 0; kt < 4; ++kt) {
        int row = ni * 16 + lr;
        int byte = row * 256 + (((kt * 32 + lg * 8) * 2) ^ ((row & 7) << 4));
        bf16x8 kf = ld_bf8(Ks, byte);
        sa[ni] = __builtin_amdgcn_mfma_f32_16x16x32_bf16(qf[kt], kf, sa[ni], 0, 0, 0);
      }
    }
    // ---- weight, causal mask, row-sum, P -> bf16 LDS ----
#pragma unroll
    for (int ni = 0; ni < 4; ++ni) {
      int sl = ni * 16 + lr;
      int sg = s0 + sl;
      float gv = garr[hbase + sg];
#pragma unroll
      for (int j = 0; j < 4; ++j) {
        int tloc = w * 16 + lg * 4 + j;
        int tg = T * 64 + tloc;
        float wgt = (sg <= tg) ? __expf(gv - Mt[j]) : 0.f;
        float val = sa[ni][j] * rs * wgt;
        nacc[j] += val;
        int byte = tloc * 128 + ((sl * 2) ^ ((tloc & 7) << 4));
        *(unsigned short*)((char*)Ps + byte) = f2bf(val);
      }
    }
    // ---- PV: h[16t][256dv] += P[16t][64s] @ Vt[256dv][64s]^T (own rows only; no barrier) ----
#pragma unroll
    for (int kt2 = 0; kt2 < 2; ++kt2) {
      int tloc = w * 16 + lr;
      int sb = (kt2 * 32 + lg * 8) * 2;
      bf16x8 pa = ld_bf8(Ps, tloc * 128 + (sb ^ ((tloc & 7) << 4)));
#pragma unroll
      for (int nv = 0; nv < 16; ++nv) {
        int dv = nv * 16 + lr;
        bf16x8 vb = ld_bf8(Vs, dv * 128 + (sb ^ ((dv & 7) << 4)));
        pv[nv] = __builtin_amdgcn_mfma_f32_16x16x32_bf16(pa, vb, pv[nv], 0, 0, 0);
      }
    }
  }
  // ---- reduce n over the 16-lane group (sum over s-cols) ----
#pragma unroll
  for (int j = 0; j < 4; ++j) {
#pragma unroll
    for (int off = 1; off < 16; off <<= 1) nacc[j] += __shfl_xor(nacc[j], off);
  }
  // ---- epilogue: h / (max(|n|, e^-m) + eps) ----
#pragma unroll
  for (int j = 0; j < 4; ++j) {
    int tg = T * 64 + w * 16 + lg * 4 + j;
    float nv = fmaxf(fabsf(nacc[j]), earr[hbase + tg]);
    float inv = 1.0f / (nv + 1e-6f);
    float* orow = hout + (size_t)tg * DMODEL + h * 256;
#pragma unroll
    for (int nvt = 0; nvt < 16; ++nvt) orow[nvt * 16 + lr] = pv[nvt][j] * inv;
  }
}

// ---------------- multihead LayerNorm (DH=256) + out-gate ----------------
__global__ __launch_bounds__(256) void mhln_gate_kernel(
    const float* __restrict__ hout, const float* __restrict__ og,
    const float* __restrict__ mhw, float* __restrict__ gact) {
  int s = blockIdx.x;
  int head = threadIdx.x >> 6, lane = threadIdx.x & 63;
  const float* hr = hout + (size_t)s * DMODEL + head * 256;
  float v0 = hr[lane], v1 = hr[lane + 64], v2 = hr[lane + 128], v3 = hr[lane + 192];
  float sum = v0 + v1 + v2 + v3;
#pragma unroll
  for (int off = 32; off > 0; off >>= 1) sum += __shfl_xor(sum, off);
  float mu = sum * (1.0f / 256.0f);
  float d0 = v0 - mu, d1 = v1 - mu, d2 = v2 - mu, d3 = v3 - mu;
  float vs = d0 * d0 + d1 * d1 + d2 * d2 + d3 * d3;
#pragma unroll
  for (int off = 32; off > 0; off >>= 1) vs += __shfl_xor(vs, off);
  float rstd = rsqrtf(vs * (1.0f / 256.0f) + 1e-6f);
  float dn[4] = {d0, d1, d2, d3};
#pragma unroll
  for (int qy = 0; qy < 4; ++qy) {
    int c = head * 256 + qy * 64 + lane;
    float ov = og[(size_t)s * DMODEL + c];
    float sig = 1.0f / (1.0f + expf(-ov));
    gact[(size_t)s * DMODEL + c] = dn[qy] * rstd * mhw[c] * sig;
  }
}

// ---------------- FFN act: G = silu(G) * U ----------------
__global__ __launch_bounds__(256) void silu_mul_kernel(
    float* __restrict__ G, const float* __restrict__ U) {
  size_t i = ((size_t)blockIdx.x * 256 + threadIdx.x) * 4;
  float4 gv = *(const float4*)(G + i);
  float4 uv = *(const float4*)(U + i);
  float4 o;
  o.x = gv.x / (1.f + expf(-gv.x)) * uv.x;
  o.y = gv.y / (1.f + expf(-gv.y)) * uv.y;
  o.z = gv.z / (1.f + expf(-gv.z)) * uv.z;
  o.w = gv.w / (1.f + expf(-gv.w)) * uv.w;
  *(float4*)(G + i) = o;
}

extern "C" void kernel_launch(void* const* d_in, const int* in_sizes, int n_in,
                              void* d_out, int out_size, void* d_ws, size_t ws_size,
                              hipStream_t stream) {
  (void)in_sizes; (void)n_in; (void)out_size; (void)ws_size;
  const int*   tok   = (const int*)d_in[0];
  const float* emb   = (const float*)d_in[1];
  const float* norm1 = (const float*)d_in[2];
  const float* Wq    = (const float*)d_in[3];
  const float* Wk    = (const float*)d_in[4];
  const float* Wv    = (const float*)d_in[5];
  const float* Wog   = (const float*)d_in[6];
  const float* Wi    = (const float*)d_in[7];
  const float* bi    = (const float*)d_in[8];
  const float* Wf    = (const float*)d_in[9];
  const float* bfp   = (const float*)d_in[10];
  const float* mhw   = (const float*)d_in[11];
  const float* Wout  = (const float*)d_in[12];
  const float* norm2 = (const float*)d_in[13];
  const float* Wg    = (const float*)d_in[14];
  const float* Wu    = (const float*)d_in[15];
  const float* Wd    = (const float*)d_in[16];
  const float* onw   = (const float*)d_in[17];
  const float* Wlm   = (const float*)d_in[18];

  float* ws = (float*)d_ws;
  const size_t M2 = 2097152;  // 2048*1024
  float* x    = ws;
  float* xm   = ws + M2;
  float* q    = ws + 2 * M2;
  float* kbuf = ws + 2 * M2 + 1048576;
  float* vT   = ws + 3 * M2;   // [1024][2048] transposed V
  float* og   = ws + 4 * M2;
  float* hout = ws + 5 * M2;
  float* gact = ws + 6 * M2;
  // FFN overlays (q..gact region dead during FFN):
  float* Gbuf = ws + 2 * M2;
  float* Ubuf = Gbuf + (size_t)2048 * 2752;
  float* ipre = Ubuf + (size_t)2048 * 2752;
  float* fpre = ipre + 8192;
  float* garr = fpre + 8192;
  float* Marr = garr + 8192;
  float* earr = Marr + 8192;

  embed_kernel<<<2048, 256, 0, stream>>>(tok, emb, x);

  for (int l = 0; l < 2; ++l) {
    const float* n1   = norm1 + (size_t)l * 1024;
    const float* wq   = Wq   + (size_t)l * 512 * 1024;
    const float* wk   = Wk   + (size_t)l * 512 * 1024;
    const float* wv   = Wv   + (size_t)l * 1024 * 1024;
    const float* wog  = Wog  + (size_t)l * 1024 * 1024;
    const float* wi   = Wi   + (size_t)l * 4 * 1024;
    const float* bil  = bi   + (size_t)l * 4;
    const float* wf   = Wf   + (size_t)l * 4 * 1024;
    const float* bfl  = bfp  + (size_t)l * 4;
    const float* mhwl = mhw  + (size_t)l * 1024;
    const float* wout = Wout + (size_t)l * 1024 * 1024;
    const float* n2   = norm2 + (size_t)l * 1024;
    const float* wg   = Wg   + (size_t)l * 2752 * 1024;
    const float* wu   = Wu   + (size_t)l * 2752 * 1024;
    const float* wd   = Wd   + (size_t)l * 1024 * 2752;

    rmsnorm_kernel<<<2048, 256, 0, stream>>>(x, n1, xm);
    gemm_kernel<0><<<dim3(4, 16), 256, 0, stream>>>(xm, wq, nullptr, q, 512, 1024);
    gemm_kernel<0><<<dim3(4, 16), 256, 0, stream>>>(xm, wk, nullptr, kbuf, 512, 1024);
    gemm_kernel<3><<<dim3(8, 16), 256, 0, stream>>>(xm, wv, nullptr, vT, 1024, 1024);
    gemm_kernel<0><<<dim3(8, 16), 256, 0, stream>>>(xm, wog, nullptr, og, 1024, 1024);
    gates_kernel<<<2048, 256, 0, stream>>>(xm, wi, bil, wf, bfl, ipre, fpre);
    scan_kernel<<<1, 256, 0, stream>>>(ipre, fpre, garr, Marr, earr);
    mlstm_mfma_kernel<<<dim3(32, 4), 256, 0, stream>>>(q, kbuf, vT, garr, Marr, earr, hout);
    mhln_gate_kernel<<<2048, 256, 0, stream>>>(hout, og, mhwl, gact);
    gemm_kernel<1><<<dim3(8, 16), 256, 0, stream>>>(gact, wout, x, x, 1024, 1024);
    rmsnorm_kernel<<<2048, 256, 0, stream>>>(x, n2, xm);
    gemm_kernel<0><<<dim3(22, 16), 256, 0, stream>>>(xm, wg, nullptr, Gbuf, 2752, 1024);
    gemm_kernel<0><<<dim3(22, 16), 256, 0, stream>>>(xm, wu, nullptr, Ubuf, 2752, 1024);
    silu_mul_kernel<<<5504, 256, 0, stream>>>(Gbuf, Ubuf);
    gemm_kernel<1><<<dim3(8, 16), 256, 0, stream>>>(Gbuf, wd, x, x, 1024, 2752);
  }

  rmsnorm_kernel<<<2048, 256, 0, stream>>>(x, onw, xm);
  gemm_kernel<2><<<dim3(250, 16), 256, 0, stream>>>(xm, Wlm, nullptr, (float*)d_out, 32000, 1024);
}

// Round 3
// 1770.669 us; speedup vs baseline: 1.3896x; 1.1852x over previous
//
#include <hip/hip_runtime.h>
#include <hip/hip_bf16.h>
#include <math.h>

// xLSTM-Large forward: S=2048, D=1024, NH=4 (Dqk=128, Dv=256), UP=2752, L=2, V=32000.
// f32 residual stream; bf16 activations for all MFMA consumers (converted once at
// the producer, RNE — numerically identical to converting at the consumer).
// Workspace peak: 14,745,600 floats = 59 MB.

#define S_LEN 2048
#define DMODEL 1024

typedef __attribute__((ext_vector_type(8))) __bf16 bf16x8;
typedef __attribute__((ext_vector_type(8))) unsigned short u16x8;
typedef __attribute__((ext_vector_type(4))) unsigned short u16x4;
typedef __attribute__((ext_vector_type(4))) float f32x4v;

union cvu { u16x8 u; bf16x8 b; };

__device__ __forceinline__ unsigned short bf_us(float f) {
  union { __bf16 b; unsigned short u; } c;
  c.b = (__bf16)f;   // RNE, native v_cvt on gfx950
  return c.u;
}

__device__ __forceinline__ u16x8 cvt8(float4 a0, float4 a1) {
  u16x8 r;
  r[0] = bf_us(a0.x); r[1] = bf_us(a0.y); r[2] = bf_us(a0.z); r[3] = bf_us(a0.w);
  r[4] = bf_us(a1.x); r[5] = bf_us(a1.y); r[6] = bf_us(a1.z); r[7] = bf_us(a1.w);
  return r;
}

__device__ __forceinline__ bf16x8 ld_bf8(const unsigned short* p, int byte_off) {
  cvu c;
  c.u = *(const u16x8*)((const char*)p + byte_off);
  return c.b;
}

// ---------------- embed ----------------
__global__ __launch_bounds__(256) void embed_kernel(
    const int* __restrict__ tok, const float* __restrict__ emb, float* __restrict__ x) {
  int s = blockIdx.x;
  int t = tok[s];
  const float4 v = *(const float4*)(emb + (size_t)t * DMODEL + threadIdx.x * 4);
  *(float4*)(x + (size_t)s * DMODEL + threadIdx.x * 4) = v;
}

// ---------------- rmsnorm (row = 1024): writes f32 + bf16 copies ----------------
__global__ __launch_bounds__(256) void rmsnorm_kernel(
    const float* __restrict__ x, const float* __restrict__ w,
    float* __restrict__ out, unsigned short* __restrict__ outb) {
  int s = blockIdx.x, tid = threadIdx.x;
  const float* xr = x + (size_t)s * DMODEL;
  float4 v = *(const float4*)(xr + tid * 4);
  float ss = v.x * v.x + v.y * v.y + v.z * v.z + v.w * v.w;
#pragma unroll
  for (int off = 32; off > 0; off >>= 1) ss += __shfl_down(ss, off);
  __shared__ float red[4];
  if ((tid & 63) == 0) red[tid >> 6] = ss;
  __syncthreads();
  float tot = red[0] + red[1] + red[2] + red[3];
  float scale = rsqrtf(tot * (1.0f / DMODEL) + 1e-6f);
  float4 wv = *(const float4*)(w + tid * 4);
  float4 o;
  o.x = v.x * scale * wv.x; o.y = v.y * scale * wv.y;
  o.z = v.z * scale * wv.z; o.w = v.w * scale * wv.w;
  *(float4*)(out + (size_t)s * DMODEL + tid * 4) = o;
  u16x4 ub;
  ub[0] = bf_us(o.x); ub[1] = bf_us(o.y); ub[2] = bf_us(o.z); ub[3] = bf_us(o.w);
  *(u16x4*)(outb + (size_t)s * DMODEL + tid * 4) = ub;
}

// ---------------- GEMM: C[M,N] = A[M,K] @ W[N,K]^T  (A bf16, W f32->bf16, f32 acc) ----
// Grid is M-major (x = M-blocks) so consecutive blocks share the W panel (L2 reuse).
// EPI: 0 f32 store | 1 f32 += X residual | 2 softcap30 f32 | 3 bf16 transposed C[N][M]
//      4 bf16 row-major | 6 silu(X)*acc -> bf16
template <int EPI>
__global__ __launch_bounds__(256) void gemm_kernel(
    const unsigned short* __restrict__ A, const float* __restrict__ W,
    const float* __restrict__ X, void* __restrict__ Cv, int N, int K) {
  __shared__ __align__(16) unsigned short As[128 * 64];
  __shared__ __align__(16) unsigned short Bs[128 * 64];
  float* C = (float*)Cv;
  unsigned short* Cb = (unsigned short*)Cv;
  const int tid = threadIdx.x;
  const int bm = blockIdx.x * 128;   // M-major
  const int bn = blockIdx.y * 128;
  const int wave = tid >> 6, lane = tid & 63;
  const int wr = (wave >> 1) * 64, wc = (wave & 1) * 64;
  const int lr = lane & 15, lhi = lane >> 4;
  f32x4v acc[4][4] = {};
  for (int k0 = 0; k0 < K; k0 += 64) {
#pragma unroll
    for (int i = 0; i < 4; ++i) {
      int gi = i * 256 + tid;          // 0..1023 : (row, 16B-group)
      int r = gi >> 3, cg = gi & 7;
      int col = ((cg ^ (r & 7)) << 3); // XOR swizzle to spread banks
      // A: bf16 direct copy (no convert)
      u16x8 ua = *(const u16x8*)(A + (size_t)(bm + r) * K + k0 + cg * 8);
      *(u16x8*)&As[r * 64 + col] = ua;
      // B: f32 load + packed convert
      int rn = bn + r;
      float4 b0 = make_float4(0.f, 0.f, 0.f, 0.f), b1 = b0;
      if (rn < N) {
        const float* srcB = W + (size_t)rn * K + k0 + cg * 8;
        b0 = *(const float4*)srcB;
        b1 = *(const float4*)(srcB + 4);
      }
      *(u16x8*)&Bs[r * 64 + col] = cvt8(b0, b1);
    }
    __syncthreads();
#pragma unroll
    for (int kk = 0; kk < 2; ++kk) {
      bf16x8 af[4], bfr[4];
      const int gc = kk * 4 + lhi;
      const int colr = ((gc ^ (lr & 7)) << 3);
#pragma unroll
      for (int mi = 0; mi < 4; ++mi) {
        int row = wr + mi * 16 + lr;
        af[mi] = *(const bf16x8*)&As[row * 64 + colr];
      }
#pragma unroll
      for (int ni = 0; ni < 4; ++ni) {
        int row = wc + ni * 16 + lr;
        bfr[ni] = *(const bf16x8*)&Bs[row * 64 + colr];
      }
#pragma unroll
      for (int mi = 0; mi < 4; ++mi)
#pragma unroll
        for (int ni = 0; ni < 4; ++ni)
          acc[mi][ni] = __builtin_amdgcn_mfma_f32_16x16x32_bf16(af[mi], bfr[ni], acc[mi][ni], 0, 0, 0);
    }
    __syncthreads();
  }
#pragma unroll
  for (int mi = 0; mi < 4; ++mi) {
#pragma unroll
    for (int ni = 0; ni < 4; ++ni) {
#pragma unroll
      for (int j = 0; j < 4; ++j) {
        int row = bm + wr + mi * 16 + lhi * 4 + j;   // C/D layout: row=(l>>4)*4+reg
        int col = bn + wc + ni * 16 + lr;            //             col=l&15
        if (col < N) {
          float v = acc[mi][ni][j];
          if (EPI == 0) C[(size_t)row * N + col] = v;
          if (EPI == 1) C[(size_t)row * N + col] = v + X[(size_t)row * N + col];
          if (EPI == 2) C[(size_t)row * N + col] = 30.0f * tanhf(v * (1.0f / 30.0f));
          if (EPI == 3) Cb[(size_t)col * S_LEN + row] = bf_us(v);
          if (EPI == 4) Cb[(size_t)row * N + col] = bf_us(v);
          if (EPI == 6) {
            float g = X[(size_t)row * N + col];
            float sv = g / (1.f + expf(-g)) * v;
            Cb[(size_t)row * N + col] = bf_us(sv);
          }
        }
      }
    }
  }
}

// ---------------- gate pre-activations: i/f = softcap15(xm @ Wi/Wf^T + b) ----------------
__global__ __launch_bounds__(256) void gates_kernel(
    const float* __restrict__ xm, const float* __restrict__ Wi, const float* __restrict__ bi,
    const float* __restrict__ Wf, const float* __restrict__ bfv,
    float* __restrict__ ipre, float* __restrict__ fpre) {
  int s = blockIdx.x;
  int head = threadIdx.x >> 6, lane = threadIdx.x & 63;
  const float* xr = xm + (size_t)s * DMODEL;
  const float* wi = Wi + head * DMODEL;
  const float* wf = Wf + head * DMODEL;
  float si = 0.f, sf = 0.f;
#pragma unroll
  for (int j = 0; j < 16; ++j) {
    float xv = xr[lane + j * 64];
    si += xv * wi[lane + j * 64];
    sf += xv * wf[lane + j * 64];
  }
#pragma unroll
  for (int off = 32; off > 0; off >>= 1) {
    si += __shfl_down(si, off);
    sf += __shfl_down(sf, off);
  }
  if (lane == 0) {
    ipre[head * S_LEN + s] = 15.0f * tanhf((si + bi[head]) * (1.0f / 15.0f));
    fpre[head * S_LEN + s] = 15.0f * tanhf((sf + bfv[head]) * (1.0f / 15.0f));
  }
}

// ---------------- per-head scan: F=cumsum(logsig(f)), g=i-F, M=cummax(g), e=exp(-(F+M)) ----
__global__ __launch_bounds__(256) void scan_kernel(
    const float* __restrict__ ipre, const float* __restrict__ fpre,
    float* __restrict__ garr, float* __restrict__ Marr, float* __restrict__ earr) {
  const int h = threadIdx.x >> 6;    // wave per head
  const int lane = threadIdx.x & 63; // lane owns 32 consecutive elements
  const int base = h * S_LEN + lane * 32;
  float lf[32];
  float lsum = 0.f;
#pragma unroll
  for (int e = 0; e < 32; ++e) {
    float f = fpre[base + e];
    float v = fminf(f, 0.f) - log1pf(expf(-fabsf(f)));  // stable log_sigmoid
    lf[e] = v;
    lsum += v;
  }
  float scan = lsum;
#pragma unroll
  for (int off = 1; off < 64; off <<= 1) {
    float t = __shfl_up(scan, off);
    if (lane >= off) scan += t;
  }
  float F0 = scan - lsum;  // exclusive prefix sum
  float gv[32];
  float F = F0, lmax = -1e30f;
#pragma unroll
  for (int e = 0; e < 32; ++e) {
    F += lf[e];
    float g = ipre[base + e] - F;
    gv[e] = g;
    lmax = fmaxf(lmax, g);
    garr[base + e] = g;
  }
  float ms = lmax;
#pragma unroll
  for (int off = 1; off < 64; off <<= 1) {
    float t = __shfl_up(ms, off);
    if (lane >= off) ms = fmaxf(ms, t);
  }
  float em = __shfl_up(ms, 1);
  if (lane == 0) em = -1e30f;  // exclusive prefix max
  float run = em;
  F = F0;
#pragma unroll
  for (int e = 0; e < 32; ++e) {
    F += lf[e];
    run = fmaxf(run, gv[e]);
    Marr[base + e] = run;
    earr[base + e] = expf(-(F + run));
  }
}

// ---------------- mLSTM parallel, bf16 MFMA flash-style (bf16 inputs) ----------------
__global__ __launch_bounds__(256) void mlstm_mfma_kernel(
    const unsigned short* __restrict__ Q, const unsigned short* __restrict__ Kb,
    const unsigned short* __restrict__ vT, const float* __restrict__ garr,
    const float* __restrict__ Marr, const float* __restrict__ earr,
    float* __restrict__ hout) {
  const int h = blockIdx.y;
  const int T = blockIdx.x;
  const int tid = threadIdx.x;
  const int w = tid >> 6, l = tid & 63;
  const int lr = l & 15, lg = l >> 4;
  const int hbase = h * S_LEN;
  const int sr = tid >> 4;   // staging: 16 rows per pass
  const int sc = tid & 15;   // staging: 16 col-groups

  __shared__ __align__(16) unsigned short Ks[64 * 128];   // [s][d] swizzled, 16 KB
  __shared__ __align__(16) unsigned short Vs[256 * 64];   // [dv][s] swizzled, 32 KB
  __shared__ __align__(16) unsigned short Ps[64 * 64];    // [t][s] swizzled, 8 KB

  // Q A-fragments: lane holds Q[t = base + lr][d = kt*32 + lg*8 .. +8]
  bf16x8 qf[4];
  {
    const unsigned short* qrow = Q + (size_t)(T * 64 + w * 16 + lr) * 512 + h * 128 + lg * 8;
#pragma unroll
    for (int kt = 0; kt < 4; ++kt) {
      cvu c;
      c.u = *(const u16x8*)(qrow + kt * 32);
      qf[kt] = c.b;
    }
  }
  float Mt[4];
#pragma unroll
  for (int j = 0; j < 4; ++j) Mt[j] = Marr[hbase + T * 64 + w * 16 + lg * 4 + j];

  f32x4v pv[16] = {};
  float nacc[4] = {0.f, 0.f, 0.f, 0.f};
  const float rs = 0.08838834764831845f;  // 1/sqrt(128)

  for (int ch = 0; ch <= T; ++ch) {
    const int s0 = ch * 64;
    __syncthreads();  // previous chunk's LDS reads done
    // ---- stage K chunk: rows s0..s0+63, 128 d (direct bf16 copy) ----
#pragma unroll
    for (int i = 0; i < 4; ++i) {
      int r = i * 16 + sr;
      u16x8 u = *(const u16x8*)(Kb + (size_t)(s0 + r) * 512 + h * 128 + sc * 8);
      int byte = r * 256 + ((sc * 16) ^ ((r & 7) << 4));
      *(u16x8*)((char*)Ks + byte) = u;
    }
    // ---- stage V^T chunk: rows dv 0..255 (head dv), cols s0..s0+63 ----
#pragma unroll
    for (int i = 0; i < 16; ++i) {
      int r = i * 16 + sr;
      u16x4 u = *(const u16x4*)(vT + (size_t)(h * 256 + r) * S_LEN + s0 + sc * 4);
      int byte = r * 128 + ((sc * 8) ^ ((r & 7) << 4));
      *(u16x4*)((char*)Vs + byte) = u;
    }
    __syncthreads();
    // ---- scores: S[t][s] tile 16x64 per wave ----
    f32x4v sa[4] = {};
#pragma unroll
    for (int ni = 0; ni < 4; ++ni) {
#pragma unroll
      for (int kt = 0; kt < 4; ++kt) {
        int row = ni * 16 + lr;
        int byte = row * 256 + (((kt * 32 + lg * 8) * 2) ^ ((row & 7) << 4));
        bf16x8 kf = ld_bf8(Ks, byte);
        sa[ni] = __builtin_amdgcn_mfma_f32_16x16x32_bf16(qf[kt], kf, sa[ni], 0, 0, 0);
      }
    }
    // ---- weight, causal mask, row-sum, P -> bf16 LDS ----
#pragma unroll
    for (int ni = 0; ni < 4; ++ni) {
      int sl = ni * 16 + lr;
      int sg = s0 + sl;
      float gv = garr[hbase + sg];
#pragma unroll
      for (int j = 0; j < 4; ++j) {
        int tloc = w * 16 + lg * 4 + j;
        int tg = T * 64 + tloc;
        float wgt = (sg <= tg) ? __expf(gv - Mt[j]) : 0.f;
        float val = sa[ni][j] * rs * wgt;
        nacc[j] += val;
        int byte = tloc * 128 + ((sl * 2) ^ ((tloc & 7) << 4));
        *(unsigned short*)((char*)Ps + byte) = bf_us(val);
      }
    }
    // ---- PV: h[16t][256dv] += P[16t][64s] @ Vt[256dv][64s]^T (own rows only) ----
#pragma unroll
    for (int kt2 = 0; kt2 < 2; ++kt2) {
      int tloc = w * 16 + lr;
      int sb = (kt2 * 32 + lg * 8) * 2;
      bf16x8 pa = ld_bf8(Ps, tloc * 128 + (sb ^ ((tloc & 7) << 4)));
#pragma unroll
      for (int nv = 0; nv < 16; ++nv) {
        int dv = nv * 16 + lr;
        bf16x8 vb = ld_bf8(Vs, dv * 128 + (sb ^ ((dv & 7) << 4)));
        pv[nv] = __builtin_amdgcn_mfma_f32_16x16x32_bf16(pa, vb, pv[nv], 0, 0, 0);
      }
    }
  }
  // ---- reduce n over the 16-lane group (sum over s-cols) ----
#pragma unroll
  for (int j = 0; j < 4; ++j) {
#pragma unroll
    for (int off = 1; off < 16; off <<= 1) nacc[j] += __shfl_xor(nacc[j], off);
  }
  // ---- epilogue: h / (max(|n|, e^-m) + eps) ----
#pragma unroll
  for (int j = 0; j < 4; ++j) {
    int tg = T * 64 + w * 16 + lg * 4 + j;
    float nv = fmaxf(fabsf(nacc[j]), earr[hbase + tg]);
    float inv = 1.0f / (nv + 1e-6f);
    float* orow = hout + (size_t)tg * DMODEL + h * 256;
#pragma unroll
    for (int nvt = 0; nvt < 16; ++nvt) orow[nvt * 16 + lr] = pv[nvt][j] * inv;
  }
}

// ---------------- multihead LayerNorm (DH=256) + out-gate; writes bf16 ----------------
__global__ __launch_bounds__(256) void mhln_gate_kernel(
    const float* __restrict__ hout, const float* __restrict__ og,
    const float* __restrict__ mhw, unsigned short* __restrict__ gact) {
  int s = blockIdx.x;
  int head = threadIdx.x >> 6, lane = threadIdx.x & 63;
  const float* hr = hout + (size_t)s * DMODEL + head * 256;
  float v0 = hr[lane], v1 = hr[lane + 64], v2 = hr[lane + 128], v3 = hr[lane + 192];
  float sum = v0 + v1 + v2 + v3;
#pragma unroll
  for (int off = 32; off > 0; off >>= 1) sum += __shfl_xor(sum, off);
  float mu = sum * (1.0f / 256.0f);
  float d0 = v0 - mu, d1 = v1 - mu, d2 = v2 - mu, d3 = v3 - mu;
  float vs = d0 * d0 + d1 * d1 + d2 * d2 + d3 * d3;
#pragma unroll
  for (int off = 32; off > 0; off >>= 1) vs += __shfl_xor(vs, off);
  float rstd = rsqrtf(vs * (1.0f / 256.0f) + 1e-6f);
  float dn[4] = {d0, d1, d2, d3};
#pragma unroll
  for (int qy = 0; qy < 4; ++qy) {
    int c = head * 256 + qy * 64 + lane;
    float ov = og[(size_t)s * DMODEL + c];
    float sig = 1.0f / (1.0f + expf(-ov));
    gact[(size_t)s * DMODEL + c] = bf_us(dn[qy] * rstd * mhw[c] * sig);
  }
}

extern "C" void kernel_launch(void* const* d_in, const int* in_sizes, int n_in,
                              void* d_out, int out_size, void* d_ws, size_t ws_size,
                              hipStream_t stream) {
  (void)in_sizes; (void)n_in; (void)out_size; (void)ws_size;
  const int*   tok   = (const int*)d_in[0];
  const float* emb   = (const float*)d_in[1];
  const float* norm1 = (const float*)d_in[2];
  const float* Wq    = (const float*)d_in[3];
  const float* Wk    = (const float*)d_in[4];
  const float* Wv    = (const float*)d_in[5];
  const float* Wog   = (const float*)d_in[6];
  const float* Wi    = (const float*)d_in[7];
  const float* bi    = (const float*)d_in[8];
  const float* Wf    = (const float*)d_in[9];
  const float* bfp   = (const float*)d_in[10];
  const float* mhw   = (const float*)d_in[11];
  const float* Wout  = (const float*)d_in[12];
  const float* norm2 = (const float*)d_in[13];
  const float* Wg    = (const float*)d_in[14];
  const float* Wu    = (const float*)d_in[15];
  const float* Wd    = (const float*)d_in[16];
  const float* onw   = (const float*)d_in[17];
  const float* Wlm   = (const float*)d_in[18];

  float* ws = (float*)d_ws;
  const size_t F = 2097152;  // 2048*1024 floats
  float*          x    = ws;                                   // [0, F)
  float*          xm   = ws + F;                               // [F, 2F)
  unsigned short* xmb  = (unsigned short*)(ws + 2 * F);        // [2F, 2.5F)
  unsigned short* gact = (unsigned short*)(ws + 2 * F + F / 2);// [2.5F, 2.75F)
  float*          ipre = ws + 2 * F + 3 * (F / 4);             // [2.75F, +40960)
  float*          fpre = ipre + 8192;
  float*          garr = fpre + 8192;
  float*          Marr = garr + 8192;
  float*          earr = Marr + 8192;
  // attention-phase buffers (dead during FFN)
  unsigned short* qb   = (unsigned short*)(ws + 3 * F);            // [3F, 3.25F)
  unsigned short* kb   = (unsigned short*)(ws + 3 * F + F / 4);    // [3.25F, 3.5F)
  unsigned short* vTb  = (unsigned short*)(ws + 3 * F + F / 2);    // [3.5F, 4F)
  float*          og   = ws + 4 * F;                               // [4F, 5F)
  float*          hout = ws + 5 * F;                               // [5F, 6F)
  // FFN overlays (share the attention region)
  float*          Gf   = ws + 3 * F;                               // [3F, 5.6875F)
  unsigned short* Gb16 = (unsigned short*)(ws + 3 * F + (size_t)2048 * 2752); // ..7.03F

  embed_kernel<<<2048, 256, 0, stream>>>(tok, emb, x);

  for (int l = 0; l < 2; ++l) {
    const float* n1   = norm1 + (size_t)l * 1024;
    const float* wq   = Wq   + (size_t)l * 512 * 1024;
    const float* wk   = Wk   + (size_t)l * 512 * 1024;
    const float* wv   = Wv   + (size_t)l * 1024 * 1024;
    const float* wog  = Wog  + (size_t)l * 1024 * 1024;
    const float* wi   = Wi   + (size_t)l * 4 * 1024;
    const float* bil  = bi   + (size_t)l * 4;
    const float* wf   = Wf   + (size_t)l * 4 * 1024;
    const float* bfl  = bfp  + (size_t)l * 4;
    const float* mhwl = mhw  + (size_t)l * 1024;
    const float* wout = Wout + (size_t)l * 1024 * 1024;
    const float* n2   = norm2 + (size_t)l * 1024;
    const float* wg   = Wg   + (size_t)l * 2752 * 1024;
    const float* wu   = Wu   + (size_t)l * 2752 * 1024;
    const float* wd   = Wd   + (size_t)l * 1024 * 2752;

    rmsnorm_kernel<<<2048, 256, 0, stream>>>(x, n1, xm, xmb);
    gemm_kernel<4><<<dim3(16, 4),  256, 0, stream>>>(xmb, wq, nullptr, qb,  512, 1024);
    gemm_kernel<4><<<dim3(16, 4),  256, 0, stream>>>(xmb, wk, nullptr, kb,  512, 1024);
    gemm_kernel<3><<<dim3(16, 8),  256, 0, stream>>>(xmb, wv, nullptr, vTb, 1024, 1024);
    gemm_kernel<0><<<dim3(16, 8),  256, 0, stream>>>(xmb, wog, nullptr, og, 1024, 1024);
    gates_kernel<<<2048, 256, 0, stream>>>(xm, wi, bil, wf, bfl, ipre, fpre);
    scan_kernel<<<1, 256, 0, stream>>>(ipre, fpre, garr, Marr, earr);
    mlstm_mfma_kernel<<<dim3(32, 4), 256, 0, stream>>>(qb, kb, vTb, garr, Marr, earr, hout);
    mhln_gate_kernel<<<2048, 256, 0, stream>>>(hout, og, mhwl, gact);
    gemm_kernel<1><<<dim3(16, 8),  256, 0, stream>>>(gact, wout, x, x, 1024, 1024);
    rmsnorm_kernel<<<2048, 256, 0, stream>>>(x, n2, xm, xmb);
    gemm_kernel<0><<<dim3(16, 22), 256, 0, stream>>>(xmb, wg, nullptr, Gf, 2752, 1024);
    gemm_kernel<6><<<dim3(16, 22), 256, 0, stream>>>(xmb, wu, Gf, Gb16, 2752, 1024);
    gemm_kernel<1><<<dim3(16, 8),  256, 0, stream>>>(Gb16, wd, x, x, 1024, 2752);
  }

  rmsnorm_kernel<<<2048, 256, 0, stream>>>(x, onw, xm, xmb);
  gemm_kernel<2><<<dim3(16, 250), 256, 0, stream>>>(xmb, Wlm, nullptr, (float*)d_out, 32000, 1024);
}

// Round 4
// 1030.966 us; speedup vs baseline: 2.3866x; 1.7175x over previous
//
#include <hip/hip_runtime.h>
#include <hip/hip_bf16.h>
#include <math.h>

// xLSTM-Large forward: S=2048, D=1024, NH=4 (Dqk=128, Dv=256), UP=2752, L=2, V=32000.
// All GEMMs: bf16 x bf16 MFMA with global_load_lds(16B) staging (m97 structure).
// Weights pre-converted f32->bf16 into workspace (RNE — bit-identical operands).
// Workspace peak: 52.7 MiB (proven budget >= 56 MiB).

#define S_LEN 2048
#define DMODEL 1024

typedef __attribute__((ext_vector_type(8))) __bf16 bf16x8;
typedef __attribute__((ext_vector_type(8))) unsigned short u16x8;
typedef __attribute__((ext_vector_type(4))) unsigned short u16x4;
typedef __attribute__((ext_vector_type(4))) float f32x4v;

union cvu { u16x8 u; bf16x8 b; };

__device__ __forceinline__ unsigned short bf_us(float f) {
  union { __bf16 b; unsigned short u; } c;
  c.b = (__bf16)f;   // RNE, native v_cvt on gfx950
  return c.u;
}
__device__ __forceinline__ float us_f(unsigned short u) {
  union { __bf16 b; unsigned short u; } c;
  c.u = u;
  return (float)c.b;
}
__device__ __forceinline__ bf16x8 ld_bf8(const unsigned short* p, int byte_off) {
  cvu c;
  c.u = *(const u16x8*)((const char*)p + byte_off);
  return c.b;
}

#define AS_G __attribute__((address_space(1)))
#define AS_L __attribute__((address_space(3)))

// stage a 128x64 bf16 tile (16 KB) from global (row stride K elems) into linear LDS
__device__ __forceinline__ void stage64(const unsigned short* gbase, int K,
                                        unsigned short* lds, int wave, int lane, int k0) {
#pragma unroll
  for (int j = 0; j < 4; ++j) {
    const int rbase = (j * 4 + wave) * 8;
    const unsigned short* src = gbase + (size_t)(rbase + (lane >> 3)) * K + k0 + (lane & 7) * 8;
    __builtin_amdgcn_global_load_lds((const AS_G void*)src,
                                     (AS_L void*)(lds + rbase * 64), 16, 0, 0);
  }
}

// ---------------- embed ----------------
__global__ __launch_bounds__(256) void embed_kernel(
    const int* __restrict__ tok, const float* __restrict__ emb, float* __restrict__ x) {
  int s = blockIdx.x;
  int t = tok[s];
  const float4 v = *(const float4*)(emb + (size_t)t * DMODEL + threadIdx.x * 4);
  *(float4*)(x + (size_t)s * DMODEL + threadIdx.x * 4) = v;
}

// ---------------- rmsnorm (row = 1024): writes bf16 ----------------
__global__ __launch_bounds__(256) void rmsnorm_kernel(
    const float* __restrict__ x, const float* __restrict__ w,
    unsigned short* __restrict__ outb) {
  int s = blockIdx.x, tid = threadIdx.x;
  const float* xr = x + (size_t)s * DMODEL;
  float4 v = *(const float4*)(xr + tid * 4);
  float ss = v.x * v.x + v.y * v.y + v.z * v.z + v.w * v.w;
#pragma unroll
  for (int off = 32; off > 0; off >>= 1) ss += __shfl_down(ss, off);
  __shared__ float red[4];
  if ((tid & 63) == 0) red[tid >> 6] = ss;
  __syncthreads();
  float tot = red[0] + red[1] + red[2] + red[3];
  float scale = rsqrtf(tot * (1.0f / DMODEL) + 1e-6f);
  float4 wv = *(const float4*)(w + tid * 4);
  u16x4 ub;
  ub[0] = bf_us(v.x * scale * wv.x);
  ub[1] = bf_us(v.y * scale * wv.y);
  ub[2] = bf_us(v.z * scale * wv.z);
  ub[3] = bf_us(v.w * scale * wv.w);
  *(u16x4*)(outb + (size_t)s * DMODEL + tid * 4) = ub;
}

// ---------------- per-layer weight convert f32 -> bf16 (with zero padding) --------
// Region layout inside W16 (elements):
//  q 0..524288 | k ..1048576 | v ..2097152 | og ..3145728 | out ..4194304 |
//  g [2816][1024] ..7077888 | u ..9961472 | d [1024][2816] ..12845056
__global__ __launch_bounds__(256) void wcvt8_kernel(
    const float* __restrict__ wq, const float* __restrict__ wk,
    const float* __restrict__ wv, const float* __restrict__ wog,
    const float* __restrict__ wout, const float* __restrict__ wg,
    const float* __restrict__ wu, const float* __restrict__ wd,
    unsigned short* __restrict__ W) {
  const int e = (blockIdx.x * 256 + threadIdx.x) * 8;
  const float* src = nullptr;
  int idx = 0;
  if (e < 524288)       { src = wq;  idx = e; }
  else if (e < 1048576) { src = wk;  idx = e - 524288; }
  else if (e < 2097152) { src = wv;  idx = e - 1048576; }
  else if (e < 3145728) { src = wog; idx = e - 2097152; }
  else if (e < 4194304) { src = wout; idx = e - 3145728; }
  else if (e < 7077888) {
    int l = e - 4194304, row = l >> 10;
    if (row < 2752) { src = wg; idx = l; }
  } else if (e < 9961472) {
    int l = e - 7077888, row = l >> 10;
    if (row < 2752) { src = wu; idx = l; }
  } else {
    int l = e - 9961472, row = l / 2816, col = l - row * 2816;
    if (col < 2752) { src = wd; idx = row * 2752 + col; }
  }
  u16x8 o;
  if (src) {
    float4 a0 = *(const float4*)(src + idx);
    float4 a1 = *(const float4*)(src + idx + 4);
    o[0] = bf_us(a0.x); o[1] = bf_us(a0.y); o[2] = bf_us(a0.z); o[3] = bf_us(a0.w);
    o[4] = bf_us(a1.x); o[5] = bf_us(a1.y); o[6] = bf_us(a1.z); o[7] = bf_us(a1.w);
  } else {
#pragma unroll
    for (int k = 0; k < 8; ++k) o[k] = 0;
  }
  *(u16x8*)(W + e) = o;
}

// ---------------- plain convert f32 -> bf16 (LM-head chunks) ----------------
__global__ __launch_bounds__(256) void cvt_kernel(
    const float* __restrict__ src, unsigned short* __restrict__ dst) {
  const int e = (blockIdx.x * 256 + threadIdx.x) * 8;
  float4 a0 = *(const float4*)(src + e);
  float4 a1 = *(const float4*)(src + e + 4);
  u16x8 o;
  o[0] = bf_us(a0.x); o[1] = bf_us(a0.y); o[2] = bf_us(a0.z); o[3] = bf_us(a0.w);
  o[4] = bf_us(a1.x); o[5] = bf_us(a1.y); o[6] = bf_us(a1.z); o[7] = bf_us(a1.w);
  *(u16x8*)(dst + e) = o;
}

// ---------------- GEMM core: C[M,N] = A[M,K] @ B[N,K]^T, bf16 x bf16 ----------------
// 128x128 tile, BK=64, 4 waves, global_load_lds staging, linear LDS.
// EPI: 1 = f32 C = acc + X (residual) | 2 = f32 softcap30 | 5 = bf16 sigmoid(acc)*X(bf16)
template <int EPI>
__global__ __launch_bounds__(256) void gemm_bb_kernel(
    const unsigned short* __restrict__ A, const unsigned short* __restrict__ B,
    const void* Xv, void* Cv, int K, int ldc) {
  __shared__ __align__(16) unsigned short As[128 * 64];
  __shared__ __align__(16) unsigned short Bs[128 * 64];
  const int tid = threadIdx.x;
  const int wave = tid >> 6, lane = tid & 63;
  const int bm = blockIdx.x * 128, bn = blockIdx.y * 128;
  const int wr = (wave >> 1) * 64, wc = (wave & 1) * 64;
  const int lr = lane & 15, lhi = lane >> 4;
  const unsigned short* Ab = A + (size_t)bm * K;
  const unsigned short* Bb = B + (size_t)bn * K;
  f32x4v acc[4][4] = {};
  for (int k0 = 0; k0 < K; k0 += 64) {
    stage64(Ab, K, As, wave, lane, k0);
    stage64(Bb, K, Bs, wave, lane, k0);
    __syncthreads();
#pragma unroll
    for (int kk = 0; kk < 2; ++kk) {
      const int gc8 = (kk * 4 + lhi) * 8;
      bf16x8 af[4], bfr[4];
#pragma unroll
      for (int mi = 0; mi < 4; ++mi) af[mi] = *(const bf16x8*)&As[(wr + mi * 16 + lr) * 64 + gc8];
#pragma unroll
      for (int ni = 0; ni < 4; ++ni) bfr[ni] = *(const bf16x8*)&Bs[(wc + ni * 16 + lr) * 64 + gc8];
#pragma unroll
      for (int mi = 0; mi < 4; ++mi)
#pragma unroll
        for (int ni = 0; ni < 4; ++ni)
          acc[mi][ni] = __builtin_amdgcn_mfma_f32_16x16x32_bf16(af[mi], bfr[ni], acc[mi][ni], 0, 0, 0);
    }
    __syncthreads();
  }
#pragma unroll
  for (int mi = 0; mi < 4; ++mi) {
#pragma unroll
    for (int ni = 0; ni < 4; ++ni) {
#pragma unroll
      for (int j = 0; j < 4; ++j) {
        int row = bm + wr + mi * 16 + lhi * 4 + j;   // C/D layout (m89)
        int col = bn + wc + ni * 16 + lr;
        float v = acc[mi][ni][j];
        if (EPI == 1)
          ((float*)Cv)[(size_t)row * ldc + col] = v + ((const float*)Xv)[(size_t)row * ldc + col];
        if (EPI == 2)
          ((float*)Cv)[(size_t)row * ldc + col] = 30.0f * tanhf(v * (1.0f / 30.0f));
        if (EPI == 5) {
          float sig = 1.0f / (1.0f + expf(-v));
          float hn = us_f(((const unsigned short*)Xv)[(size_t)row * ldc + col]);
          ((unsigned short*)Cv)[(size_t)row * ldc + col] = bf_us(hn * sig);
        }
      }
    }
  }
}

// ---------------- fused QKV GEMM (q,k bf16 row-major; v bf16 transposed) --------
__global__ __launch_bounds__(256) void qkv_kernel(
    const unsigned short* __restrict__ A, const unsigned short* __restrict__ Wq16,
    const unsigned short* __restrict__ Wk16, const unsigned short* __restrict__ Wv16,
    unsigned short* __restrict__ qb, unsigned short* __restrict__ kb,
    unsigned short* __restrict__ vTb) {
  __shared__ __align__(16) unsigned short As[128 * 64];
  __shared__ __align__(16) unsigned short Bs[128 * 64];
  const int by = blockIdx.y;
  const unsigned short* B;
  int bnl, mode;
  if (by < 4)      { B = Wq16; bnl = by * 128; mode = 0; }
  else if (by < 8) { B = Wk16; bnl = (by - 4) * 128; mode = 1; }
  else             { B = Wv16; bnl = (by - 8) * 128; mode = 2; }
  const int K = 1024;
  const int tid = threadIdx.x;
  const int wave = tid >> 6, lane = tid & 63;
  const int bm = blockIdx.x * 128;
  const int wr = (wave >> 1) * 64, wc = (wave & 1) * 64;
  const int lr = lane & 15, lhi = lane >> 4;
  const unsigned short* Ab = A + (size_t)bm * K;
  const unsigned short* Bb = B + (size_t)bnl * K;
  f32x4v acc[4][4] = {};
  for (int k0 = 0; k0 < K; k0 += 64) {
    stage64(Ab, K, As, wave, lane, k0);
    stage64(Bb, K, Bs, wave, lane, k0);
    __syncthreads();
#pragma unroll
    for (int kk = 0; kk < 2; ++kk) {
      const int gc8 = (kk * 4 + lhi) * 8;
      bf16x8 af[4], bfr[4];
#pragma unroll
      for (int mi = 0; mi < 4; ++mi) af[mi] = *(const bf16x8*)&As[(wr + mi * 16 + lr) * 64 + gc8];
#pragma unroll
      for (int ni = 0; ni < 4; ++ni) bfr[ni] = *(const bf16x8*)&Bs[(wc + ni * 16 + lr) * 64 + gc8];
#pragma unroll
      for (int mi = 0; mi < 4; ++mi)
#pragma unroll
        for (int ni = 0; ni < 4; ++ni)
          acc[mi][ni] = __builtin_amdgcn_mfma_f32_16x16x32_bf16(af[mi], bfr[ni], acc[mi][ni], 0, 0, 0);
    }
    __syncthreads();
  }
#pragma unroll
  for (int mi = 0; mi < 4; ++mi) {
#pragma unroll
    for (int ni = 0; ni < 4; ++ni) {
#pragma unroll
      for (int j = 0; j < 4; ++j) {
        int row = bm + wr + mi * 16 + lhi * 4 + j;
        int col = bnl + wc + ni * 16 + lr;
        unsigned short o = bf_us(acc[mi][ni][j]);
        if (mode == 0) qb[(size_t)row * 512 + col] = o;
        else if (mode == 1) kb[(size_t)row * 512 + col] = o;
        else vTb[(size_t)col * S_LEN + row] = o;
      }
    }
  }
}

// ---------------- fused FFN gate+up GEMM: Gb = silu(A Wg^T) * (A Wu^T), bf16 -------
__global__ __launch_bounds__(256) void ffn_kernel(
    const unsigned short* __restrict__ A, const unsigned short* __restrict__ Bg,
    const unsigned short* __restrict__ Bu, unsigned short* __restrict__ Gb) {
  __shared__ __align__(16) unsigned short As[128 * 64];
  __shared__ __align__(16) unsigned short Bgs[128 * 64];
  __shared__ __align__(16) unsigned short Bus[128 * 64];
  const int K = 1024;
  const int tid = threadIdx.x;
  const int wave = tid >> 6, lane = tid & 63;
  const int bm = blockIdx.x * 128, bn = blockIdx.y * 128;
  const int wr = (wave >> 1) * 64, wc = (wave & 1) * 64;
  const int lr = lane & 15, lhi = lane >> 4;
  const unsigned short* Ab = A + (size_t)bm * K;
  const unsigned short* Bgb = Bg + (size_t)bn * K;
  const unsigned short* Bub = Bu + (size_t)bn * K;
  f32x4v accg[4][4] = {};
  f32x4v accu[4][4] = {};
  for (int k0 = 0; k0 < K; k0 += 64) {
    stage64(Ab, K, As, wave, lane, k0);
    stage64(Bgb, K, Bgs, wave, lane, k0);
    stage64(Bub, K, Bus, wave, lane, k0);
    __syncthreads();
#pragma unroll
    for (int kk = 0; kk < 2; ++kk) {
      const int gc8 = (kk * 4 + lhi) * 8;
      bf16x8 af[4], bg[4], bu[4];
#pragma unroll
      for (int mi = 0; mi < 4; ++mi) af[mi] = *(const bf16x8*)&As[(wr + mi * 16 + lr) * 64 + gc8];
#pragma unroll
      for (int ni = 0; ni < 4; ++ni) bg[ni] = *(const bf16x8*)&Bgs[(wc + ni * 16 + lr) * 64 + gc8];
#pragma unroll
      for (int ni = 0; ni < 4; ++ni) bu[ni] = *(const bf16x8*)&Bus[(wc + ni * 16 + lr) * 64 + gc8];
#pragma unroll
      for (int mi = 0; mi < 4; ++mi)
#pragma unroll
        for (int ni = 0; ni < 4; ++ni) {
          accg[mi][ni] = __builtin_amdgcn_mfma_f32_16x16x32_bf16(af[mi], bg[ni], accg[mi][ni], 0, 0, 0);
          accu[mi][ni] = __builtin_amdgcn_mfma_f32_16x16x32_bf16(af[mi], bu[ni], accu[mi][ni], 0, 0, 0);
        }
    }
    __syncthreads();
  }
#pragma unroll
  for (int mi = 0; mi < 4; ++mi) {
#pragma unroll
    for (int ni = 0; ni < 4; ++ni) {
#pragma unroll
      for (int j = 0; j < 4; ++j) {
        int row = bm + wr + mi * 16 + lhi * 4 + j;
        int col = bn + wc + ni * 16 + lr;
        float g = accg[mi][ni][j];
        float sv = g / (1.f + expf(-g)) * accu[mi][ni][j];
        Gb[(size_t)row * 2816 + col] = bf_us(sv);
      }
    }
  }
}

// ---------------- gate pre-activations (inline rmsnorm from f32 x) ----------------
__global__ __launch_bounds__(256) void gates_kernel(
    const float* __restrict__ x, const float* __restrict__ n1,
    const float* __restrict__ Wi, const float* __restrict__ bi,
    const float* __restrict__ Wf, const float* __restrict__ bfv,
    float* __restrict__ ipre, float* __restrict__ fpre) {
  int s = blockIdx.x;
  int head = threadIdx.x >> 6, lane = threadIdx.x & 63;
  const float* xr = x + (size_t)s * DMODEL;
  float xv[16];
  float ss = 0.f;
#pragma unroll
  for (int j = 0; j < 16; ++j) { xv[j] = xr[lane + j * 64]; ss += xv[j] * xv[j]; }
#pragma unroll
  for (int off = 32; off > 0; off >>= 1) ss += __shfl_xor(ss, off);
  float scale = rsqrtf(ss * (1.0f / DMODEL) + 1e-6f);
  const float* wi = Wi + head * DMODEL;
  const float* wf = Wf + head * DMODEL;
  float si = 0.f, sf = 0.f;
#pragma unroll
  for (int j = 0; j < 16; ++j) {
    int c = lane + j * 64;
    float xm = xv[j] * scale * n1[c];
    si += xm * wi[c];
    sf += xm * wf[c];
  }
#pragma unroll
  for (int off = 32; off > 0; off >>= 1) {
    si += __shfl_down(si, off);
    sf += __shfl_down(sf, off);
  }
  if (lane == 0) {
    ipre[head * S_LEN + s] = 15.0f * tanhf((si + bi[head]) * (1.0f / 15.0f));
    fpre[head * S_LEN + s] = 15.0f * tanhf((sf + bfv[head]) * (1.0f / 15.0f));
  }
}

// ---------------- per-head scan ----------------
__global__ __launch_bounds__(256) void scan_kernel(
    const float* __restrict__ ipre, const float* __restrict__ fpre,
    float* __restrict__ garr, float* __restrict__ Marr, float* __restrict__ earr) {
  const int h = threadIdx.x >> 6;
  const int lane = threadIdx.x & 63;
  const int base = h * S_LEN + lane * 32;
  float lf[32];
  float lsum = 0.f;
#pragma unroll
  for (int e = 0; e < 32; ++e) {
    float f = fpre[base + e];
    float v = fminf(f, 0.f) - log1pf(expf(-fabsf(f)));
    lf[e] = v;
    lsum += v;
  }
  float scan = lsum;
#pragma unroll
  for (int off = 1; off < 64; off <<= 1) {
    float t = __shfl_up(scan, off);
    if (lane >= off) scan += t;
  }
  float F0 = scan - lsum;
  float gv[32];
  float F = F0, lmax = -1e30f;
#pragma unroll
  for (int e = 0; e < 32; ++e) {
    F += lf[e];
    float g = ipre[base + e] - F;
    gv[e] = g;
    lmax = fmaxf(lmax, g);
    garr[base + e] = g;
  }
  float ms = lmax;
#pragma unroll
  for (int off = 1; off < 64; off <<= 1) {
    float t = __shfl_up(ms, off);
    if (lane >= off) ms = fmaxf(ms, t);
  }
  float em = __shfl_up(ms, 1);
  if (lane == 0) em = -1e30f;
  float run = em;
  F = F0;
#pragma unroll
  for (int e = 0; e < 32; ++e) {
    F += lf[e];
    run = fmaxf(run, gv[e]);
    Marr[base + e] = run;
    earr[base + e] = expf(-(F + run));
  }
}

// ---------------- mLSTM parallel, bf16 MFMA flash-style ----------------
__global__ __launch_bounds__(256) void mlstm_mfma_kernel(
    const unsigned short* __restrict__ Q, const unsigned short* __restrict__ Kb,
    const unsigned short* __restrict__ vT, const float* __restrict__ garr,
    const float* __restrict__ Marr, const float* __restrict__ earr,
    float* __restrict__ hout) {
  const int h = blockIdx.y;
  const int T = blockIdx.x;
  const int tid = threadIdx.x;
  const int w = tid >> 6, l = tid & 63;
  const int lr = l & 15, lg = l >> 4;
  const int hbase = h * S_LEN;
  const int sr = tid >> 4;
  const int sc = tid & 15;

  __shared__ __align__(16) unsigned short Ks[64 * 128];
  __shared__ __align__(16) unsigned short Vs[256 * 64];
  __shared__ __align__(16) unsigned short Ps[64 * 64];

  bf16x8 qf[4];
  {
    const unsigned short* qrow = Q + (size_t)(T * 64 + w * 16 + lr) * 512 + h * 128 + lg * 8;
#pragma unroll
    for (int kt = 0; kt < 4; ++kt) {
      cvu c;
      c.u = *(const u16x8*)(qrow + kt * 32);
      qf[kt] = c.b;
    }
  }
  float Mt[4];
#pragma unroll
  for (int j = 0; j < 4; ++j) Mt[j] = Marr[hbase + T * 64 + w * 16 + lg * 4 + j];

  f32x4v pv[16] = {};
  float nacc[4] = {0.f, 0.f, 0.f, 0.f};
  const float rs = 0.08838834764831845f;  // 1/sqrt(128)

  for (int ch = 0; ch <= T; ++ch) {
    const int s0 = ch * 64;
    __syncthreads();
#pragma unroll
    for (int i = 0; i < 4; ++i) {
      int r = i * 16 + sr;
      u16x8 u = *(const u16x8*)(Kb + (size_t)(s0 + r) * 512 + h * 128 + sc * 8);
      int byte = r * 256 + ((sc * 16) ^ ((r & 7) << 4));
      *(u16x8*)((char*)Ks + byte) = u;
    }
#pragma unroll
    for (int i = 0; i < 16; ++i) {
      int r = i * 16 + sr;
      u16x4 u = *(const u16x4*)(vT + (size_t)(h * 256 + r) * S_LEN + s0 + sc * 4);
      int byte = r * 128 + ((sc * 8) ^ ((r & 7) << 4));
      *(u16x4*)((char*)Vs + byte) = u;
    }
    __syncthreads();
    f32x4v sa[4] = {};
#pragma unroll
    for (int ni = 0; ni < 4; ++ni) {
#pragma unroll
      for (int kt = 0; kt < 4; ++kt) {
        int row = ni * 16 + lr;
        int byte = row * 256 + (((kt * 32 + lg * 8) * 2) ^ ((row & 7) << 4));
        bf16x8 kf = ld_bf8(Ks, byte);
        sa[ni] = __builtin_amdgcn_mfma_f32_16x16x32_bf16(qf[kt], kf, sa[ni], 0, 0, 0);
      }
    }
#pragma unroll
    for (int ni = 0; ni < 4; ++ni) {
      int sl = ni * 16 + lr;
      int sg = s0 + sl;
      float gv = garr[hbase + sg];
#pragma unroll
      for (int j = 0; j < 4; ++j) {
        int tloc = w * 16 + lg * 4 + j;
        int tg = T * 64 + tloc;
        float wgt = (sg <= tg) ? __expf(gv - Mt[j]) : 0.f;
        float val = sa[ni][j] * rs * wgt;
        nacc[j] += val;
        int byte = tloc * 128 + ((sl * 2) ^ ((tloc & 7) << 4));
        *(unsigned short*)((char*)Ps + byte) = bf_us(val);
      }
    }
#pragma unroll
    for (int kt2 = 0; kt2 < 2; ++kt2) {
      int tloc = w * 16 + lr;
      int sb = (kt2 * 32 + lg * 8) * 2;
      bf16x8 pa = ld_bf8(Ps, tloc * 128 + (sb ^ ((tloc & 7) << 4)));
#pragma unroll
      for (int nv = 0; nv < 16; ++nv) {
        int dv = nv * 16 + lr;
        bf16x8 vb = ld_bf8(Vs, dv * 128 + (sb ^ ((dv & 7) << 4)));
        pv[nv] = __builtin_amdgcn_mfma_f32_16x16x32_bf16(pa, vb, pv[nv], 0, 0, 0);
      }
    }
  }
#pragma unroll
  for (int j = 0; j < 4; ++j) {
#pragma unroll
    for (int off = 1; off < 16; off <<= 1) nacc[j] += __shfl_xor(nacc[j], off);
  }
#pragma unroll
  for (int j = 0; j < 4; ++j) {
    int tg = T * 64 + w * 16 + lg * 4 + j;
    float nv = fmaxf(fabsf(nacc[j]), earr[hbase + tg]);
    float inv = 1.0f / (nv + 1e-6f);
    float* orow = hout + (size_t)tg * DMODEL + h * 256;
#pragma unroll
    for (int nvt = 0; nvt < 16; ++nvt) orow[nvt * 16 + lr] = pv[nvt][j] * inv;
  }
}

// ---------------- multihead LayerNorm (DH=256) * mhw -> bf16 ----------------
__global__ __launch_bounds__(256) void mhln_kernel(
    const float* __restrict__ hout, const float* __restrict__ mhw,
    unsigned short* __restrict__ hnb) {
  int s = blockIdx.x;
  int head = threadIdx.x >> 6, lane = threadIdx.x & 63;
  const float* hr = hout + (size_t)s * DMODEL + head * 256;
  float v0 = hr[lane], v1 = hr[lane + 64], v2 = hr[lane + 128], v3 = hr[lane + 192];
  float sum = v0 + v1 + v2 + v3;
#pragma unroll
  for (int off = 32; off > 0; off >>= 1) sum += __shfl_xor(sum, off);
  float mu = sum * (1.0f / 256.0f);
  float d0 = v0 - mu, d1 = v1 - mu, d2 = v2 - mu, d3 = v3 - mu;
  float vs = d0 * d0 + d1 * d1 + d2 * d2 + d3 * d3;
#pragma unroll
  for (int off = 32; off > 0; off >>= 1) vs += __shfl_xor(vs, off);
  float rstd = rsqrtf(vs * (1.0f / 256.0f) + 1e-6f);
  float dn[4] = {d0, d1, d2, d3};
#pragma unroll
  for (int qy = 0; qy < 4; ++qy) {
    int c = head * 256 + qy * 64 + lane;
    hnb[(size_t)s * DMODEL + c] = bf_us(dn[qy] * rstd * mhw[c]);
  }
}

extern "C" void kernel_launch(void* const* d_in, const int* in_sizes, int n_in,
                              void* d_out, int out_size, void* d_ws, size_t ws_size,
                              hipStream_t stream) {
  (void)in_sizes; (void)n_in; (void)out_size; (void)ws_size;
  const int*   tok   = (const int*)d_in[0];
  const float* emb   = (const float*)d_in[1];
  const float* norm1 = (const float*)d_in[2];
  const float* Wq    = (const float*)d_in[3];
  const float* Wk    = (const float*)d_in[4];
  const float* Wv    = (const float*)d_in[5];
  const float* Wog   = (const float*)d_in[6];
  const float* Wi    = (const float*)d_in[7];
  const float* bi    = (const float*)d_in[8];
  const float* Wf    = (const float*)d_in[9];
  const float* bfp   = (const float*)d_in[10];
  const float* mhw   = (const float*)d_in[11];
  const float* Wout  = (const float*)d_in[12];
  const float* norm2 = (const float*)d_in[13];
  const float* Wg    = (const float*)d_in[14];
  const float* Wu    = (const float*)d_in[15];
  const float* Wd    = (const float*)d_in[16];
  const float* onw   = (const float*)d_in[17];
  const float* Wlm   = (const float*)d_in[18];

  char* wsb = (char*)d_ws;
  float*          x    = (float*)wsb;                          // 8 MiB
  unsigned short* xmb  = (unsigned short*)(wsb + 8388608);     // 4 MiB
  float*          ipre = (float*)(wsb + 12582912);             // 5 x 32 KiB
  float*          fpre = ipre + 8192;
  float*          garr = fpre + 8192;
  float*          Marr = garr + 8192;
  float*          earr = Marr + 8192;
  unsigned short* W16  = (unsigned short*)(wsb + 12746752);    // 24.5 MiB
  // W16 region offsets (elements)
  const size_t OQ = 0, OKk = 524288, OV = 1048576, OOG = 2097152, OOUT = 3145728,
               OGt = 4194304, OU = 7077888, OD = 9961472;
  char* P = wsb + 38436864;                                    // phase region, 16 MiB
  unsigned short* qb   = (unsigned short*)P;                   // 2 MiB
  unsigned short* kb   = (unsigned short*)(P + 2097152);       // 2 MiB
  unsigned short* vTb  = (unsigned short*)(P + 4194304);       // 4 MiB
  float*          hout = (float*)(P + 8388608);                // 8 MiB
  unsigned short* hnb  = (unsigned short*)P;                   // overlay qb+kb
  unsigned short* gact = (unsigned short*)(P + 4194304);       // overlay vTb
  unsigned short* Gb16 = (unsigned short*)P;                   // FFN overlay, 11 MiB
  unsigned short* wlm16 = (unsigned short*)P;                  // LM overlay, 16 MiB

  embed_kernel<<<2048, 256, 0, stream>>>(tok, emb, x);

  for (int l = 0; l < 2; ++l) {
    const float* n1   = norm1 + (size_t)l * 1024;
    const float* wqv  = Wq   + (size_t)l * 512 * 1024;
    const float* wkv  = Wk   + (size_t)l * 512 * 1024;
    const float* wvv  = Wv   + (size_t)l * 1024 * 1024;
    const float* wogv = Wog  + (size_t)l * 1024 * 1024;
    const float* wiv  = Wi   + (size_t)l * 4 * 1024;
    const float* bil  = bi   + (size_t)l * 4;
    const float* wfv  = Wf   + (size_t)l * 4 * 1024;
    const float* bfl  = bfp  + (size_t)l * 4;
    const float* mhwl = mhw  + (size_t)l * 1024;
    const float* wov  = Wout + (size_t)l * 1024 * 1024;
    const float* n2   = norm2 + (size_t)l * 1024;
    const float* wgv  = Wg   + (size_t)l * 2752 * 1024;
    const float* wuv  = Wu   + (size_t)l * 2752 * 1024;
    const float* wdv  = Wd   + (size_t)l * 1024 * 2752;

    rmsnorm_kernel<<<2048, 256, 0, stream>>>(x, n1, xmb);
    wcvt8_kernel<<<6272, 256, 0, stream>>>(wqv, wkv, wvv, wogv, wov, wgv, wuv, wdv, W16);
    qkv_kernel<<<dim3(16, 16), 256, 0, stream>>>(xmb, W16 + OQ, W16 + OKk, W16 + OV,
                                                 qb, kb, vTb);
    gates_kernel<<<2048, 256, 0, stream>>>(x, n1, wiv, bil, wfv, bfl, ipre, fpre);
    scan_kernel<<<1, 256, 0, stream>>>(ipre, fpre, garr, Marr, earr);
    mlstm_mfma_kernel<<<dim3(32, 4), 256, 0, stream>>>(qb, kb, vTb, garr, Marr, earr, hout);
    mhln_kernel<<<2048, 256, 0, stream>>>(hout, mhwl, hnb);
    gemm_bb_kernel<5><<<dim3(16, 8), 256, 0, stream>>>(xmb, W16 + OOG, hnb, gact, 1024, 1024);
    gemm_bb_kernel<1><<<dim3(16, 8), 256, 0, stream>>>(gact, W16 + OOUT, x, x, 1024, 1024);
    rmsnorm_kernel<<<2048, 256, 0, stream>>>(x, n2, xmb);
    ffn_kernel<<<dim3(16, 22), 256, 0, stream>>>(xmb, W16 + OGt, W16 + OU, Gb16);
    gemm_bb_kernel<1><<<dim3(16, 8), 256, 0, stream>>>(Gb16, W16 + OD, x, x, 2816, 1024);
  }

  rmsnorm_kernel<<<2048, 256, 0, stream>>>(x, onw, xmb);
  for (int c = 0; c < 4; ++c) {
    const int Nc = (c < 3) ? 8192 : 7424;
    cvt_kernel<<<(Nc * 1024) / 2048, 256, 0, stream>>>(Wlm + (size_t)c * 8192 * 1024, wlm16);
    gemm_bb_kernel<2><<<dim3(16, Nc / 128), 256, 0, stream>>>(
        xmb, wlm16, nullptr, (float*)d_out + (size_t)c * 8192, 1024, 32000);
  }
}

// Round 5
// 965.484 us; speedup vs baseline: 2.5485x; 1.0678x over previous
//
#include <hip/hip_runtime.h>
#include <hip/hip_bf16.h>
#include <math.h>

// xLSTM-Large forward: S=2048, D=1024, NH=4 (Dqk=128, Dv=256), UP=2752, L=2, V=32000.
// All GEMMs: bf16 x bf16 MFMA, global_load_lds(16B) staging, 2-phase double-buffered
// (T3 minimum recipe: stage next K-tile before computing current; __syncthreads drains).
// Weights pre-converted f32->bf16 in workspace (RNE — bit-identical operands).
// Workspace peak ~163 MiB (ws_size ≈ 1000 MiB per harness poison fill).

#define S_LEN 2048
#define DMODEL 1024

typedef __attribute__((ext_vector_type(8))) __bf16 bf16x8;
typedef __attribute__((ext_vector_type(8))) unsigned short u16x8;
typedef __attribute__((ext_vector_type(4))) unsigned short u16x4;
typedef __attribute__((ext_vector_type(4))) float f32x4v;

union cvu { u16x8 u; bf16x8 b; };

__device__ __forceinline__ unsigned short bf_us(float f) {
  union { __bf16 b; unsigned short u; } c;
  c.b = (__bf16)f;   // RNE, native v_cvt on gfx950
  return c.u;
}
__device__ __forceinline__ float us_f(unsigned short u) {
  union { __bf16 b; unsigned short u; } c;
  c.u = u;
  return (float)c.b;
}
__device__ __forceinline__ bf16x8 ld_bf8(const unsigned short* p, int byte_off) {
  cvu c;
  c.u = *(const u16x8*)((const char*)p + byte_off);
  return c.b;
}

#define AS_G __attribute__((address_space(1)))
#define AS_L __attribute__((address_space(3)))

// stage a 128x64 bf16 tile (16 KB) from global (row stride K elems) into linear LDS
__device__ __forceinline__ void stage64(const unsigned short* gbase, int K,
                                        unsigned short* lds, int wave, int lane, int k0) {
#pragma unroll
  for (int j = 0; j < 4; ++j) {
    const int rbase = (j * 4 + wave) * 8;
    const unsigned short* src = gbase + (size_t)(rbase + (lane >> 3)) * K + k0 + (lane & 7) * 8;
    __builtin_amdgcn_global_load_lds((const AS_G void*)src,
                                     (AS_L void*)(lds + rbase * 64), 16, 0, 0);
  }
}

// ---------------- embed ----------------
__global__ __launch_bounds__(256) void embed_kernel(
    const int* __restrict__ tok, const float* __restrict__ emb, float* __restrict__ x) {
  int s = blockIdx.x;
  int t = tok[s];
  const float4 v = *(const float4*)(emb + (size_t)t * DMODEL + threadIdx.x * 4);
  *(float4*)(x + (size_t)s * DMODEL + threadIdx.x * 4) = v;
}

// ---------------- rmsnorm (row = 1024): writes bf16 ----------------
__global__ __launch_bounds__(256) void rmsnorm_kernel(
    const float* __restrict__ x, const float* __restrict__ w,
    unsigned short* __restrict__ outb) {
  int s = blockIdx.x, tid = threadIdx.x;
  const float* xr = x + (size_t)s * DMODEL;
  float4 v = *(const float4*)(xr + tid * 4);
  float ss = v.x * v.x + v.y * v.y + v.z * v.z + v.w * v.w;
#pragma unroll
  for (int off = 32; off > 0; off >>= 1) ss += __shfl_down(ss, off);
  __shared__ float red[4];
  if ((tid & 63) == 0) red[tid >> 6] = ss;
  __syncthreads();
  float tot = red[0] + red[1] + red[2] + red[3];
  float scale = rsqrtf(tot * (1.0f / DMODEL) + 1e-6f);
  float4 wv = *(const float4*)(w + tid * 4);
  u16x4 ub;
  ub[0] = bf_us(v.x * scale * wv.x);
  ub[1] = bf_us(v.y * scale * wv.y);
  ub[2] = bf_us(v.z * scale * wv.z);
  ub[3] = bf_us(v.w * scale * wv.w);
  *(u16x4*)(outb + (size_t)s * DMODEL + tid * 4) = ub;
}

// ---------------- per-layer weight convert f32 -> bf16 (with zero padding) --------
// Region layout inside W16 (elements):
//  q 0..524288 | k ..1048576 | v ..2097152 | og ..3145728 | out ..4194304 |
//  g [2816][1024] ..7077888 | u ..9961472 | d [1024][2816] ..12845056
__global__ __launch_bounds__(256) void wcvt8_kernel(
    const float* __restrict__ wq, const float* __restrict__ wk,
    const float* __restrict__ wv, const float* __restrict__ wog,
    const float* __restrict__ wout, const float* __restrict__ wg,
    const float* __restrict__ wu, const float* __restrict__ wd,
    unsigned short* __restrict__ W) {
  const int e = (blockIdx.x * 256 + threadIdx.x) * 8;
  const float* src = nullptr;
  int idx = 0;
  if (e < 524288)       { src = wq;  idx = e; }
  else if (e < 1048576) { src = wk;  idx = e - 524288; }
  else if (e < 2097152) { src = wv;  idx = e - 1048576; }
  else if (e < 3145728) { src = wog; idx = e - 2097152; }
  else if (e < 4194304) { src = wout; idx = e - 3145728; }
  else if (e < 7077888) {
    int l = e - 4194304, row = l >> 10;
    if (row < 2752) { src = wg; idx = l; }
  } else if (e < 9961472) {
    int l = e - 7077888, row = l >> 10;
    if (row < 2752) { src = wu; idx = l; }
  } else {
    int l = e - 9961472, row = l / 2816, col = l - row * 2816;
    if (col < 2752) { src = wd; idx = row * 2752 + col; }
  }
  u16x8 o;
  if (src) {
    float4 a0 = *(const float4*)(src + idx);
    float4 a1 = *(const float4*)(src + idx + 4);
    o[0] = bf_us(a0.x); o[1] = bf_us(a0.y); o[2] = bf_us(a0.z); o[3] = bf_us(a0.w);
    o[4] = bf_us(a1.x); o[5] = bf_us(a1.y); o[6] = bf_us(a1.z); o[7] = bf_us(a1.w);
  } else {
#pragma unroll
    for (int k = 0; k < 8; ++k) o[k] = 0;
  }
  *(u16x8*)(W + e) = o;
}

// ---------------- plain convert f32 -> bf16 (LM head) ----------------
__global__ __launch_bounds__(256) void cvt_kernel(
    const float* __restrict__ src, unsigned short* __restrict__ dst) {
  const int e = (blockIdx.x * 256 + threadIdx.x) * 8;
  float4 a0 = *(const float4*)(src + e);
  float4 a1 = *(const float4*)(src + e + 4);
  u16x8 o;
  o[0] = bf_us(a0.x); o[1] = bf_us(a0.y); o[2] = bf_us(a0.z); o[3] = bf_us(a0.w);
  o[4] = bf_us(a1.x); o[5] = bf_us(a1.y); o[6] = bf_us(a1.z); o[7] = bf_us(a1.w);
  *(u16x8*)(dst + e) = o;
}

// ---------------- GEMM core: C[M,N] = A[M,K] @ B[N,K]^T, bf16 x bf16 ----------------
// 128x128 tile, BK=64, 4 waves, 2-phase double-buffered global_load_lds staging.
// K must be a multiple of 128 (NK even).
// EPI: 0 f32 store | 1 f32 acc+X residual | 2 f32 softcap30 | 5 bf16 sigmoid(acc)*X(bf16)
//      6 bf16 silu(X_f32)*acc
template <int EPI>
__global__ __launch_bounds__(256) void gemm_bb_kernel(
    const unsigned short* __restrict__ A, const unsigned short* __restrict__ B,
    const void* Xv, void* Cv, int K, int ldc) {
  __shared__ __align__(16) unsigned short As[2][128 * 64];
  __shared__ __align__(16) unsigned short Bs[2][128 * 64];
  const int tid = threadIdx.x;
  const int wave = tid >> 6, lane = tid & 63;
  const int bm = blockIdx.x * 128, bn = blockIdx.y * 128;
  const int wr = (wave >> 1) * 64, wc = (wave & 1) * 64;
  const int lr = lane & 15, lhi = lane >> 4;
  const unsigned short* Ab = A + (size_t)bm * K;
  const unsigned short* Bb = B + (size_t)bn * K;
  f32x4v acc[4][4] = {};

  auto compute = [&](const unsigned short* As_, const unsigned short* Bs_) {
#pragma unroll
    for (int kk = 0; kk < 2; ++kk) {
      const int gc8 = (kk * 4 + lhi) * 8;
      bf16x8 af[4], bfr[4];
#pragma unroll
      for (int mi = 0; mi < 4; ++mi) af[mi] = *(const bf16x8*)&As_[(wr + mi * 16 + lr) * 64 + gc8];
#pragma unroll
      for (int ni = 0; ni < 4; ++ni) bfr[ni] = *(const bf16x8*)&Bs_[(wc + ni * 16 + lr) * 64 + gc8];
#pragma unroll
      for (int mi = 0; mi < 4; ++mi)
#pragma unroll
        for (int ni = 0; ni < 4; ++ni)
          acc[mi][ni] = __builtin_amdgcn_mfma_f32_16x16x32_bf16(af[mi], bfr[ni], acc[mi][ni], 0, 0, 0);
    }
  };

  const int NK = K >> 6;  // even
  stage64(Ab, K, As[0], wave, lane, 0);
  stage64(Bb, K, Bs[0], wave, lane, 0);
  __syncthreads();
  for (int it = 0; it < NK; it += 2) {
    stage64(Ab, K, As[1], wave, lane, (it + 1) << 6);
    stage64(Bb, K, Bs[1], wave, lane, (it + 1) << 6);
    compute(As[0], Bs[0]);
    __syncthreads();
    if (it + 2 < NK) {
      stage64(Ab, K, As[0], wave, lane, (it + 2) << 6);
      stage64(Bb, K, Bs[0], wave, lane, (it + 2) << 6);
    }
    compute(As[1], Bs[1]);
    __syncthreads();
  }
#pragma unroll
  for (int mi = 0; mi < 4; ++mi) {
#pragma unroll
    for (int ni = 0; ni < 4; ++ni) {
#pragma unroll
      for (int j = 0; j < 4; ++j) {
        int row = bm + wr + mi * 16 + lhi * 4 + j;   // C/D layout (m89)
        int col = bn + wc + ni * 16 + lr;
        float v = acc[mi][ni][j];
        if (EPI == 0)
          ((float*)Cv)[(size_t)row * ldc + col] = v;
        if (EPI == 1)
          ((float*)Cv)[(size_t)row * ldc + col] = v + ((const float*)Xv)[(size_t)row * ldc + col];
        if (EPI == 2)
          ((float*)Cv)[(size_t)row * ldc + col] = 30.0f * tanhf(v * (1.0f / 30.0f));
        if (EPI == 5) {
          float sig = 1.0f / (1.0f + expf(-v));
          float hn = us_f(((const unsigned short*)Xv)[(size_t)row * ldc + col]);
          ((unsigned short*)Cv)[(size_t)row * ldc + col] = bf_us(hn * sig);
        }
        if (EPI == 6) {
          float g = ((const float*)Xv)[(size_t)row * ldc + col];
          float sv = g / (1.f + expf(-g)) * v;
          ((unsigned short*)Cv)[(size_t)row * ldc + col] = bf_us(sv);
        }
      }
    }
  }
}

// ---------------- fused QKV GEMM (q,k bf16 row-major; v bf16 transposed) --------
__global__ __launch_bounds__(256) void qkv_kernel(
    const unsigned short* __restrict__ A, const unsigned short* __restrict__ Wq16,
    const unsigned short* __restrict__ Wk16, const unsigned short* __restrict__ Wv16,
    unsigned short* __restrict__ qb, unsigned short* __restrict__ kb,
    unsigned short* __restrict__ vTb) {
  __shared__ __align__(16) unsigned short As[2][128 * 64];
  __shared__ __align__(16) unsigned short Bs[2][128 * 64];
  const int by = blockIdx.y;
  const unsigned short* B;
  int bnl, mode;
  if (by < 4)      { B = Wq16; bnl = by * 128; mode = 0; }
  else if (by < 8) { B = Wk16; bnl = (by - 4) * 128; mode = 1; }
  else             { B = Wv16; bnl = (by - 8) * 128; mode = 2; }
  const int K = 1024;
  const int tid = threadIdx.x;
  const int wave = tid >> 6, lane = tid & 63;
  const int bm = blockIdx.x * 128;
  const int wr = (wave >> 1) * 64, wc = (wave & 1) * 64;
  const int lr = lane & 15, lhi = lane >> 4;
  const unsigned short* Ab = A + (size_t)bm * K;
  const unsigned short* Bb = B + (size_t)bnl * K;
  f32x4v acc[4][4] = {};

  auto compute = [&](const unsigned short* As_, const unsigned short* Bs_) {
#pragma unroll
    for (int kk = 0; kk < 2; ++kk) {
      const int gc8 = (kk * 4 + lhi) * 8;
      bf16x8 af[4], bfr[4];
#pragma unroll
      for (int mi = 0; mi < 4; ++mi) af[mi] = *(const bf16x8*)&As_[(wr + mi * 16 + lr) * 64 + gc8];
#pragma unroll
      for (int ni = 0; ni < 4; ++ni) bfr[ni] = *(const bf16x8*)&Bs_[(wc + ni * 16 + lr) * 64 + gc8];
#pragma unroll
      for (int mi = 0; mi < 4; ++mi)
#pragma unroll
        for (int ni = 0; ni < 4; ++ni)
          acc[mi][ni] = __builtin_amdgcn_mfma_f32_16x16x32_bf16(af[mi], bfr[ni], acc[mi][ni], 0, 0, 0);
    }
  };

  const int NK = 16;
  stage64(Ab, K, As[0], wave, lane, 0);
  stage64(Bb, K, Bs[0], wave, lane, 0);
  __syncthreads();
  for (int it = 0; it < NK; it += 2) {
    stage64(Ab, K, As[1], wave, lane, (it + 1) << 6);
    stage64(Bb, K, Bs[1], wave, lane, (it + 1) << 6);
    compute(As[0], Bs[0]);
    __syncthreads();
    if (it + 2 < NK) {
      stage64(Ab, K, As[0], wave, lane, (it + 2) << 6);
      stage64(Bb, K, Bs[0], wave, lane, (it + 2) << 6);
    }
    compute(As[1], Bs[1]);
    __syncthreads();
  }
#pragma unroll
  for (int mi = 0; mi < 4; ++mi) {
#pragma unroll
    for (int ni = 0; ni < 4; ++ni) {
#pragma unroll
      for (int j = 0; j < 4; ++j) {
        int row = bm + wr + mi * 16 + lhi * 4 + j;
        int col = bnl + wc + ni * 16 + lr;
        unsigned short o = bf_us(acc[mi][ni][j]);
        if (mode == 0) qb[(size_t)row * 512 + col] = o;
        else if (mode == 1) kb[(size_t)row * 512 + col] = o;
        else vTb[(size_t)col * S_LEN + row] = o;
      }
    }
  }
}

// ---------------- gate pre-activations (inline rmsnorm from f32 x) ----------------
__global__ __launch_bounds__(256) void gates_kernel(
    const float* __restrict__ x, const float* __restrict__ n1,
    const float* __restrict__ Wi, const float* __restrict__ bi,
    const float* __restrict__ Wf, const float* __restrict__ bfv,
    float* __restrict__ ipre, float* __restrict__ fpre) {
  int s = blockIdx.x;
  int head = threadIdx.x >> 6, lane = threadIdx.x & 63;
  const float* xr = x + (size_t)s * DMODEL;
  float xv[16];
  float ss = 0.f;
#pragma unroll
  for (int j = 0; j < 16; ++j) { xv[j] = xr[lane + j * 64]; ss += xv[j] * xv[j]; }
#pragma unroll
  for (int off = 32; off > 0; off >>= 1) ss += __shfl_xor(ss, off);
  float scale = rsqrtf(ss * (1.0f / DMODEL) + 1e-6f);
  const float* wi = Wi + head * DMODEL;
  const float* wf = Wf + head * DMODEL;
  float si = 0.f, sf = 0.f;
#pragma unroll
  for (int j = 0; j < 16; ++j) {
    int c = lane + j * 64;
    float xm = xv[j] * scale * n1[c];
    si += xm * wi[c];
    sf += xm * wf[c];
  }
#pragma unroll
  for (int off = 32; off > 0; off >>= 1) {
    si += __shfl_down(si, off);
    sf += __shfl_down(sf, off);
  }
  if (lane == 0) {
    ipre[head * S_LEN + s] = 15.0f * tanhf((si + bi[head]) * (1.0f / 15.0f));
    fpre[head * S_LEN + s] = 15.0f * tanhf((sf + bfv[head]) * (1.0f / 15.0f));
  }
}

// ---------------- per-head scan ----------------
__global__ __launch_bounds__(256) void scan_kernel(
    const float* __restrict__ ipre, const float* __restrict__ fpre,
    float* __restrict__ garr, float* __restrict__ Marr, float* __restrict__ earr) {
  const int h = threadIdx.x >> 6;
  const int lane = threadIdx.x & 63;
  const int base = h * S_LEN + lane * 32;
  float lf[32];
  float lsum = 0.f;
#pragma unroll
  for (int e = 0; e < 32; ++e) {
    float f = fpre[base + e];
    float v = fminf(f, 0.f) - log1pf(expf(-fabsf(f)));
    lf[e] = v;
    lsum += v;
  }
  float scan = lsum;
#pragma unroll
  for (int off = 1; off < 64; off <<= 1) {
    float t = __shfl_up(scan, off);
    if (lane >= off) scan += t;
  }
  float F0 = scan - lsum;
  float gv[32];
  float F = F0, lmax = -1e30f;
#pragma unroll
  for (int e = 0; e < 32; ++e) {
    F += lf[e];
    float g = ipre[base + e] - F;
    gv[e] = g;
    lmax = fmaxf(lmax, g);
    garr[base + e] = g;
  }
  float ms = lmax;
#pragma unroll
  for (int off = 1; off < 64; off <<= 1) {
    float t = __shfl_up(ms, off);
    if (lane >= off) ms = fmaxf(ms, t);
  }
  float em = __shfl_up(ms, 1);
  if (lane == 0) em = -1e30f;
  float run = em;
  F = F0;
#pragma unroll
  for (int e = 0; e < 32; ++e) {
    F += lf[e];
    run = fmaxf(run, gv[e]);
    Marr[base + e] = run;
    earr[base + e] = expf(-(F + run));
  }
}

// ---------------- mLSTM parallel, bf16 MFMA flash-style ----------------
__global__ __launch_bounds__(256) void mlstm_mfma_kernel(
    const unsigned short* __restrict__ Q, const unsigned short* __restrict__ Kb,
    const unsigned short* __restrict__ vT, const float* __restrict__ garr,
    const float* __restrict__ Marr, const float* __restrict__ earr,
    float* __restrict__ hout) {
  const int h = blockIdx.y;
  const int T = blockIdx.x;
  const int tid = threadIdx.x;
  const int w = tid >> 6, l = tid & 63;
  const int lr = l & 15, lg = l >> 4;
  const int hbase = h * S_LEN;
  const int sr = tid >> 4;
  const int sc = tid & 15;

  __shared__ __align__(16) unsigned short Ks[64 * 128];
  __shared__ __align__(16) unsigned short Vs[256 * 64];
  __shared__ __align__(16) unsigned short Ps[64 * 64];

  bf16x8 qf[4];
  {
    const unsigned short* qrow = Q + (size_t)(T * 64 + w * 16 + lr) * 512 + h * 128 + lg * 8;
#pragma unroll
    for (int kt = 0; kt < 4; ++kt) {
      cvu c;
      c.u = *(const u16x8*)(qrow + kt * 32);
      qf[kt] = c.b;
    }
  }
  float Mt[4];
#pragma unroll
  for (int j = 0; j < 4; ++j) Mt[j] = Marr[hbase + T * 64 + w * 16 + lg * 4 + j];

  f32x4v pv[16] = {};
  float nacc[4] = {0.f, 0.f, 0.f, 0.f};
  const float rs = 0.08838834764831845f;  // 1/sqrt(128)

  for (int ch = 0; ch <= T; ++ch) {
    const int s0 = ch * 64;
    __syncthreads();
#pragma unroll
    for (int i = 0; i < 4; ++i) {
      int r = i * 16 + sr;
      u16x8 u = *(const u16x8*)(Kb + (size_t)(s0 + r) * 512 + h * 128 + sc * 8);
      int byte = r * 256 + ((sc * 16) ^ ((r & 7) << 4));
      *(u16x8*)((char*)Ks + byte) = u;
    }
#pragma unroll
    for (int i = 0; i < 16; ++i) {
      int r = i * 16 + sr;
      u16x4 u = *(const u16x4*)(vT + (size_t)(h * 256 + r) * S_LEN + s0 + sc * 4);
      int byte = r * 128 + ((sc * 8) ^ ((r & 7) << 4));
      *(u16x4*)((char*)Vs + byte) = u;
    }
    __syncthreads();
    f32x4v sa[4] = {};
#pragma unroll
    for (int ni = 0; ni < 4; ++ni) {
#pragma unroll
      for (int kt = 0; kt < 4; ++kt) {
        int row = ni * 16 + lr;
        int byte = row * 256 + (((kt * 32 + lg * 8) * 2) ^ ((row & 7) << 4));
        bf16x8 kf = ld_bf8(Ks, byte);
        sa[ni] = __builtin_amdgcn_mfma_f32_16x16x32_bf16(qf[kt], kf, sa[ni], 0, 0, 0);
      }
    }
#pragma unroll
    for (int ni = 0; ni < 4; ++ni) {
      int sl = ni * 16 + lr;
      int sg = s0 + sl;
      float gv = garr[hbase + sg];
#pragma unroll
      for (int j = 0; j < 4; ++j) {
        int tloc = w * 16 + lg * 4 + j;
        int tg = T * 64 + tloc;
        float wgt = (sg <= tg) ? __expf(gv - Mt[j]) : 0.f;
        float val = sa[ni][j] * rs * wgt;
        nacc[j] += val;
        int byte = tloc * 128 + ((sl * 2) ^ ((tloc & 7) << 4));
        *(unsigned short*)((char*)Ps + byte) = bf_us(val);
      }
    }
#pragma unroll
    for (int kt2 = 0; kt2 < 2; ++kt2) {
      int tloc = w * 16 + lr;
      int sb = (kt2 * 32 + lg * 8) * 2;
      bf16x8 pa = ld_bf8(Ps, tloc * 128 + (sb ^ ((tloc & 7) << 4)));
#pragma unroll
      for (int nv = 0; nv < 16; ++nv) {
        int dv = nv * 16 + lr;
        bf16x8 vb = ld_bf8(Vs, dv * 128 + (sb ^ ((dv & 7) << 4)));
        pv[nv] = __builtin_amdgcn_mfma_f32_16x16x32_bf16(pa, vb, pv[nv], 0, 0, 0);
      }
    }
  }
#pragma unroll
  for (int j = 0; j < 4; ++j) {
#pragma unroll
    for (int off = 1; off < 16; off <<= 1) nacc[j] += __shfl_xor(nacc[j], off);
  }
#pragma unroll
  for (int j = 0; j < 4; ++j) {
    int tg = T * 64 + w * 16 + lg * 4 + j;
    float nv = fmaxf(fabsf(nacc[j]), earr[hbase + tg]);
    float inv = 1.0f / (nv + 1e-6f);
    float* orow = hout + (size_t)tg * DMODEL + h * 256;
#pragma unroll
    for (int nvt = 0; nvt < 16; ++nvt) orow[nvt * 16 + lr] = pv[nvt][j] * inv;
  }
}

// ---------------- multihead LayerNorm (DH=256) * mhw -> bf16 ----------------
__global__ __launch_bounds__(256) void mhln_kernel(
    const float* __restrict__ hout, const float* __restrict__ mhw,
    unsigned short* __restrict__ hnb) {
  int s = blockIdx.x;
  int head = threadIdx.x >> 6, lane = threadIdx.x & 63;
  const float* hr = hout + (size_t)s * DMODEL + head * 256;
  float v0 = hr[lane], v1 = hr[lane + 64], v2 = hr[lane + 128], v3 = hr[lane + 192];
  float sum = v0 + v1 + v2 + v3;
#pragma unroll
  for (int off = 32; off > 0; off >>= 1) sum += __shfl_xor(sum, off);
  float mu = sum * (1.0f / 256.0f);
  float d0 = v0 - mu, d1 = v1 - mu, d2 = v2 - mu, d3 = v3 - mu;
  float vs = d0 * d0 + d1 * d1 + d2 * d2 + d3 * d3;
#pragma unroll
  for (int off = 32; off > 0; off >>= 1) vs += __shfl_xor(vs, off);
  float rstd = rsqrtf(vs * (1.0f / 256.0f) + 1e-6f);
  float dn[4] = {d0, d1, d2, d3};
#pragma unroll
  for (int qy = 0; qy < 4; ++qy) {
    int c = head * 256 + qy * 64 + lane;
    hnb[(size_t)s * DMODEL + c] = bf_us(dn[qy] * rstd * mhw[c]);
  }
}

extern "C" void kernel_launch(void* const* d_in, const int* in_sizes, int n_in,
                              void* d_out, int out_size, void* d_ws, size_t ws_size,
                              hipStream_t stream) {
  (void)in_sizes; (void)n_in; (void)out_size; (void)ws_size;
  const int*   tok   = (const int*)d_in[0];
  const float* emb   = (const float*)d_in[1];
  const float* norm1 = (const float*)d_in[2];
  const float* Wq    = (const float*)d_in[3];
  const float* Wk    = (const float*)d_in[4];
  const float* Wv    = (const float*)d_in[5];
  const float* Wog   = (const float*)d_in[6];
  const float* Wi    = (const float*)d_in[7];
  const float* bi    = (const float*)d_in[8];
  const float* Wf    = (const float*)d_in[9];
  const float* bfp   = (const float*)d_in[10];
  const float* mhw   = (const float*)d_in[11];
  const float* Wout  = (const float*)d_in[12];
  const float* norm2 = (const float*)d_in[13];
  const float* Wg    = (const float*)d_in[14];
  const float* Wu    = (const float*)d_in[15];
  const float* Wd    = (const float*)d_in[16];
  const float* onw   = (const float*)d_in[17];
  const float* Wlm   = (const float*)d_in[18];

  char* wsb = (char*)d_ws;
  const size_t MB = 1ull << 20;
  float*          x    = (float*)wsb;                          // 8 MiB
  unsigned short* xmb  = (unsigned short*)(wsb + 8 * MB);      // 4 MiB
  float*          ipre = (float*)(wsb + 12 * MB);              // 5 x 32 KiB
  float*          fpre = ipre + 8192;
  float*          garr = fpre + 8192;
  float*          Marr = garr + 8192;
  float*          earr = Marr + 8192;
  unsigned short* W16  = (unsigned short*)(wsb + 13 * MB);     // 24.5 MiB -> ends 37.5
  const size_t OQ = 0, OKk = 524288, OV = 1048576, OOG = 2097152, OOUT = 3145728,
               OGt = 4194304, OU = 7077888, OD = 9961472;
  unsigned short* qb    = (unsigned short*)(wsb + 38 * MB);    // 2 MiB
  unsigned short* kb    = (unsigned short*)(wsb + 40 * MB);    // 2 MiB
  unsigned short* vTb   = (unsigned short*)(wsb + 42 * MB);    // 4 MiB
  float*          hout  = (float*)(wsb + 46 * MB);             // 8 MiB
  unsigned short* hnb   = (unsigned short*)(wsb + 54 * MB);    // 4 MiB
  unsigned short* gact  = (unsigned short*)(wsb + 58 * MB);    // 4 MiB
  float*          Gf    = (float*)(wsb + 62 * MB);             // 22 MiB -> ends 84
  unsigned short* Gb16  = (unsigned short*)(wsb + 86 * MB);    // 11 MiB -> ends 97
  unsigned short* wlm16 = (unsigned short*)(wsb + 100 * MB);   // 62.5 MiB -> ends 162.5

  embed_kernel<<<2048, 256, 0, stream>>>(tok, emb, x);

  for (int l = 0; l < 2; ++l) {
    const float* n1   = norm1 + (size_t)l * 1024;
    const float* wqv  = Wq   + (size_t)l * 512 * 1024;
    const float* wkv  = Wk   + (size_t)l * 512 * 1024;
    const float* wvv  = Wv   + (size_t)l * 1024 * 1024;
    const float* wogv = Wog  + (size_t)l * 1024 * 1024;
    const float* wiv  = Wi   + (size_t)l * 4 * 1024;
    const float* bil  = bi   + (size_t)l * 4;
    const float* wfv  = Wf   + (size_t)l * 4 * 1024;
    const float* bfl  = bfp  + (size_t)l * 4;
    const float* mhwl = mhw  + (size_t)l * 1024;
    const float* wov  = Wout + (size_t)l * 1024 * 1024;
    const float* n2   = norm2 + (size_t)l * 1024;
    const float* wgv  = Wg   + (size_t)l * 2752 * 1024;
    const float* wuv  = Wu   + (size_t)l * 2752 * 1024;
    const float* wdv  = Wd   + (size_t)l * 1024 * 2752;

    rmsnorm_kernel<<<2048, 256, 0, stream>>>(x, n1, xmb);
    wcvt8_kernel<<<6272, 256, 0, stream>>>(wqv, wkv, wvv, wogv, wov, wgv, wuv, wdv, W16);
    qkv_kernel<<<dim3(16, 16), 256, 0, stream>>>(xmb, W16 + OQ, W16 + OKk, W16 + OV,
                                                 qb, kb, vTb);
    gates_kernel<<<2048, 256, 0, stream>>>(x, n1, wiv, bil, wfv, bfl, ipre, fpre);
    scan_kernel<<<1, 256, 0, stream>>>(ipre, fpre, garr, Marr, earr);
    mlstm_mfma_kernel<<<dim3(32, 4), 256, 0, stream>>>(qb, kb, vTb, garr, Marr, earr, hout);
    mhln_kernel<<<2048, 256, 0, stream>>>(hout, mhwl, hnb);
    gemm_bb_kernel<5><<<dim3(16, 8), 256, 0, stream>>>(xmb, W16 + OOG, hnb, gact, 1024, 1024);
    gemm_bb_kernel<1><<<dim3(16, 8), 256, 0, stream>>>(gact, W16 + OOUT, x, x, 1024, 1024);
    rmsnorm_kernel<<<2048, 256, 0, stream>>>(x, n2, xmb);
    gemm_bb_kernel<0><<<dim3(16, 22), 256, 0, stream>>>(xmb, W16 + OGt, nullptr, Gf, 1024, 2816);
    gemm_bb_kernel<6><<<dim3(16, 22), 256, 0, stream>>>(xmb, W16 + OU, Gf, Gb16, 1024, 2816);
    gemm_bb_kernel<1><<<dim3(16, 8), 256, 0, stream>>>(Gb16, W16 + OD, x, x, 2816, 1024);
  }

  rmsnorm_kernel<<<2048, 256, 0, stream>>>(x, onw, xmb);
  cvt_kernel<<<16000, 256, 0, stream>>>(Wlm, wlm16);
  gemm_bb_kernel<2><<<dim3(16, 250), 256, 0, stream>>>(
      xmb, wlm16, nullptr, (float*)d_out, 1024, 32000);
}

// Round 6
// 909.020 us; speedup vs baseline: 2.7068x; 1.0621x over previous
//
#include <hip/hip_runtime.h>
#include <hip/hip_bf16.h>
#include <math.h>

// xLSTM-Large forward: S=2048, D=1024, NH=4 (Dqk=128, Dv=256), UP=2752, L=2, V=32000.
// All GEMMs: bf16 x bf16 MFMA, global_load_lds(16B) staging, 2-phase double-buffered,
// XOR-swizzled LDS via pre-swizzled SOURCE + swizzled READ (rule #21: linear DMA dest).
// Weights pre-converted f32->bf16 in workspace (RNE — bit-identical operands).

#define S_LEN 2048
#define DMODEL 1024

typedef __attribute__((ext_vector_type(8))) __bf16 bf16x8;
typedef __attribute__((ext_vector_type(8))) unsigned short u16x8;
typedef __attribute__((ext_vector_type(4))) unsigned short u16x4;
typedef __attribute__((ext_vector_type(4))) float f32x4v;

union cvu { u16x8 u; bf16x8 b; };

__device__ __forceinline__ unsigned short bf_us(float f) {
  union { __bf16 b; unsigned short u; } c;
  c.b = (__bf16)f;   // RNE, native v_cvt on gfx950
  return c.u;
}
__device__ __forceinline__ float us_f(unsigned short u) {
  union { __bf16 b; unsigned short u; } c;
  c.u = u;
  return (float)c.b;
}
__device__ __forceinline__ bf16x8 ld_bf8(const unsigned short* p, int byte_off) {
  cvu c;
  c.u = *(const u16x8*)((const char*)p + byte_off);
  return c.b;
}

#define AS_G __attribute__((address_space(1)))
#define AS_L __attribute__((address_space(3)))

// Stage a 128x64 bf16 tile (16 KB) from global (row stride K elems) into LDS.
// LDS dest is linear (DMA requirement); the global SOURCE column-group is
// pre-swizzled (cg ^= row&7) so that a matching XOR on the read side yields
// conflict-free ds_read_b128 (rule #21: source perm == read perm, involution).
__device__ __forceinline__ void stage64(const unsigned short* gbase, int K,
                                        unsigned short* lds, int wave, int lane, int k0) {
#pragma unroll
  for (int j = 0; j < 4; ++j) {
    const int rbase = (j * 4 + wave) * 8;
    const int r = rbase + (lane >> 3);
    const int cg = (lane & 7) ^ (r & 7);   // pre-swizzled source column group
    const unsigned short* src = gbase + (size_t)r * K + k0 + cg * 8;
    __builtin_amdgcn_global_load_lds((const AS_G void*)src,
                                     (AS_L void*)(lds + rbase * 64), 16, 0, 0);
  }
}

// ---------------- embed ----------------
__global__ __launch_bounds__(256) void embed_kernel(
    const int* __restrict__ tok, const float* __restrict__ emb, float* __restrict__ x) {
  int s = blockIdx.x;
  int t = tok[s];
  const float4 v = *(const float4*)(emb + (size_t)t * DMODEL + threadIdx.x * 4);
  *(float4*)(x + (size_t)s * DMODEL + threadIdx.x * 4) = v;
}

// ---------------- rmsnorm (row = 1024): writes bf16 ----------------
__global__ __launch_bounds__(256) void rmsnorm_kernel(
    const float* __restrict__ x, const float* __restrict__ w,
    unsigned short* __restrict__ outb) {
  int s = blockIdx.x, tid = threadIdx.x;
  const float* xr = x + (size_t)s * DMODEL;
  float4 v = *(const float4*)(xr + tid * 4);
  float ss = v.x * v.x + v.y * v.y + v.z * v.z + v.w * v.w;
#pragma unroll
  for (int off = 32; off > 0; off >>= 1) ss += __shfl_down(ss, off);
  __shared__ float red[4];
  if ((tid & 63) == 0) red[tid >> 6] = ss;
  __syncthreads();
  float tot = red[0] + red[1] + red[2] + red[3];
  float scale = rsqrtf(tot * (1.0f / DMODEL) + 1e-6f);
  float4 wv = *(const float4*)(w + tid * 4);
  u16x4 ub;
  ub[0] = bf_us(v.x * scale * wv.x);
  ub[1] = bf_us(v.y * scale * wv.y);
  ub[2] = bf_us(v.z * scale * wv.z);
  ub[3] = bf_us(v.w * scale * wv.w);
  *(u16x4*)(outb + (size_t)s * DMODEL + tid * 4) = ub;
}

// ---------------- per-layer weight convert f32 -> bf16 (with zero padding) --------
__global__ __launch_bounds__(256) void wcvt8_kernel(
    const float* __restrict__ wq, const float* __restrict__ wk,
    const float* __restrict__ wv, const float* __restrict__ wog,
    const float* __restrict__ wout, const float* __restrict__ wg,
    const float* __restrict__ wu, const float* __restrict__ wd,
    unsigned short* __restrict__ W) {
  const int e = (blockIdx.x * 256 + threadIdx.x) * 8;
  const float* src = nullptr;
  int idx = 0;
  if (e < 524288)       { src = wq;  idx = e; }
  else if (e < 1048576) { src = wk;  idx = e - 524288; }
  else if (e < 2097152) { src = wv;  idx = e - 1048576; }
  else if (e < 3145728) { src = wog; idx = e - 2097152; }
  else if (e < 4194304) { src = wout; idx = e - 3145728; }
  else if (e < 7077888) {
    int l = e - 4194304, row = l >> 10;
    if (row < 2752) { src = wg; idx = l; }
  } else if (e < 9961472) {
    int l = e - 7077888, row = l >> 10;
    if (row < 2752) { src = wu; idx = l; }
  } else {
    int l = e - 9961472, row = l / 2816, col = l - row * 2816;
    if (col < 2752) { src = wd; idx = row * 2752 + col; }
  }
  u16x8 o;
  if (src) {
    float4 a0 = *(const float4*)(src + idx);
    float4 a1 = *(const float4*)(src + idx + 4);
    o[0] = bf_us(a0.x); o[1] = bf_us(a0.y); o[2] = bf_us(a0.z); o[3] = bf_us(a0.w);
    o[4] = bf_us(a1.x); o[5] = bf_us(a1.y); o[6] = bf_us(a1.z); o[7] = bf_us(a1.w);
  } else {
#pragma unroll
    for (int k = 0; k < 8; ++k) o[k] = 0;
  }
  *(u16x8*)(W + e) = o;
}

// ---------------- plain convert f32 -> bf16 (LM head) ----------------
__global__ __launch_bounds__(256) void cvt_kernel(
    const float* __restrict__ src, unsigned short* __restrict__ dst) {
  const int e = (blockIdx.x * 256 + threadIdx.x) * 8;
  float4 a0 = *(const float4*)(src + e);
  float4 a1 = *(const float4*)(src + e + 4);
  u16x8 o;
  o[0] = bf_us(a0.x); o[1] = bf_us(a0.y); o[2] = bf_us(a0.z); o[3] = bf_us(a0.w);
  o[4] = bf_us(a1.x); o[5] = bf_us(a1.y); o[6] = bf_us(a1.z); o[7] = bf_us(a1.w);
  *(u16x8*)(dst + e) = o;
}

// ---------------- GEMM core: C[M,N] = A[M,K] @ B[N,K]^T, bf16 x bf16 ----------------
// 128x128 tile, BK=64, 4 waves, 2-phase double-buffered global_load_lds staging,
// swizzled LDS (pre-swizzled source + XOR read). K must be a multiple of 128.
// EPI: 0 f32 store | 1 f32 acc+X residual | 2 f32 softcap30 | 5 bf16 sigmoid(acc)*X(bf16)
//      6 bf16 silu(X_f32)*acc
template <int EPI>
__global__ __launch_bounds__(256) void gemm_bb_kernel(
    const unsigned short* __restrict__ A, const unsigned short* __restrict__ B,
    const void* Xv, void* Cv, int K, int ldc) {
  __shared__ __align__(16) unsigned short As[2][128 * 64];
  __shared__ __align__(16) unsigned short Bs[2][128 * 64];
  const int tid = threadIdx.x;
  const int wave = tid >> 6, lane = tid & 63;
  const int bm = blockIdx.x * 128, bn = blockIdx.y * 128;
  const int wr = (wave >> 1) * 64, wc = (wave & 1) * 64;
  const int lr = lane & 15, lhi = lane >> 4;
  const unsigned short* Ab = A + (size_t)bm * K;
  const unsigned short* Bb = B + (size_t)bn * K;
  f32x4v acc[4][4] = {};

  auto compute = [&](const unsigned short* As_, const unsigned short* Bs_) {
#pragma unroll
    for (int kk = 0; kk < 2; ++kk) {
      const int sw = (((kk * 4 + lhi) ^ (lr & 7)) << 3);  // swizzled col offset
      bf16x8 af[4], bfr[4];
#pragma unroll
      for (int mi = 0; mi < 4; ++mi) af[mi] = *(const bf16x8*)&As_[(wr + mi * 16 + lr) * 64 + sw];
#pragma unroll
      for (int ni = 0; ni < 4; ++ni) bfr[ni] = *(const bf16x8*)&Bs_[(wc + ni * 16 + lr) * 64 + sw];
#pragma unroll
      for (int mi = 0; mi < 4; ++mi)
#pragma unroll
        for (int ni = 0; ni < 4; ++ni)
          acc[mi][ni] = __builtin_amdgcn_mfma_f32_16x16x32_bf16(af[mi], bfr[ni], acc[mi][ni], 0, 0, 0);
    }
  };

  const int NK = K >> 6;  // even
  stage64(Ab, K, As[0], wave, lane, 0);
  stage64(Bb, K, Bs[0], wave, lane, 0);
  __syncthreads();
  for (int it = 0; it < NK; it += 2) {
    stage64(Ab, K, As[1], wave, lane, (it + 1) << 6);
    stage64(Bb, K, Bs[1], wave, lane, (it + 1) << 6);
    compute(As[0], Bs[0]);
    __syncthreads();
    if (it + 2 < NK) {
      stage64(Ab, K, As[0], wave, lane, (it + 2) << 6);
      stage64(Bb, K, Bs[0], wave, lane, (it + 2) << 6);
    }
    compute(As[1], Bs[1]);
    __syncthreads();
  }
#pragma unroll
  for (int mi = 0; mi < 4; ++mi) {
#pragma unroll
    for (int ni = 0; ni < 4; ++ni) {
#pragma unroll
      for (int j = 0; j < 4; ++j) {
        int row = bm + wr + mi * 16 + lhi * 4 + j;   // C/D layout (m89)
        int col = bn + wc + ni * 16 + lr;
        float v = acc[mi][ni][j];
        if (EPI == 0)
          ((float*)Cv)[(size_t)row * ldc + col] = v;
        if (EPI == 1)
          ((float*)Cv)[(size_t)row * ldc + col] = v + ((const float*)Xv)[(size_t)row * ldc + col];
        if (EPI == 2)
          ((float*)Cv)[(size_t)row * ldc + col] = 30.0f * tanhf(v * (1.0f / 30.0f));
        if (EPI == 5) {
          float sig = 1.0f / (1.0f + expf(-v));
          float hn = us_f(((const unsigned short*)Xv)[(size_t)row * ldc + col]);
          ((unsigned short*)Cv)[(size_t)row * ldc + col] = bf_us(hn * sig);
        }
        if (EPI == 6) {
          float g = ((const float*)Xv)[(size_t)row * ldc + col];
          float sv = g / (1.f + expf(-g)) * v;
          ((unsigned short*)Cv)[(size_t)row * ldc + col] = bf_us(sv);
        }
      }
    }
  }
}

// ---------------- fused QKV GEMM (q,k bf16 row-major; v bf16 transposed) --------
__global__ __launch_bounds__(256) void qkv_kernel(
    const unsigned short* __restrict__ A, const unsigned short* __restrict__ Wq16,
    const unsigned short* __restrict__ Wk16, const unsigned short* __restrict__ Wv16,
    unsigned short* __restrict__ qb, unsigned short* __restrict__ kb,
    unsigned short* __restrict__ vTb) {
  __shared__ __align__(16) unsigned short As[2][128 * 64];
  __shared__ __align__(16) unsigned short Bs[2][128 * 64];
  const int by = blockIdx.y;
  const unsigned short* B;
  int bnl, mode;
  if (by < 4)      { B = Wq16; bnl = by * 128; mode = 0; }
  else if (by < 8) { B = Wk16; bnl = (by - 4) * 128; mode = 1; }
  else             { B = Wv16; bnl = (by - 8) * 128; mode = 2; }
  const int K = 1024;
  const int tid = threadIdx.x;
  const int wave = tid >> 6, lane = tid & 63;
  const int bm = blockIdx.x * 128;
  const int wr = (wave >> 1) * 64, wc = (wave & 1) * 64;
  const int lr = lane & 15, lhi = lane >> 4;
  const unsigned short* Ab = A + (size_t)bm * K;
  const unsigned short* Bb = B + (size_t)bnl * K;
  f32x4v acc[4][4] = {};

  auto compute = [&](const unsigned short* As_, const unsigned short* Bs_) {
#pragma unroll
    for (int kk = 0; kk < 2; ++kk) {
      const int sw = (((kk * 4 + lhi) ^ (lr & 7)) << 3);
      bf16x8 af[4], bfr[4];
#pragma unroll
      for (int mi = 0; mi < 4; ++mi) af[mi] = *(const bf16x8*)&As_[(wr + mi * 16 + lr) * 64 + sw];
#pragma unroll
      for (int ni = 0; ni < 4; ++ni) bfr[ni] = *(const bf16x8*)&Bs_[(wc + ni * 16 + lr) * 64 + sw];
#pragma unroll
      for (int mi = 0; mi < 4; ++mi)
#pragma unroll
        for (int ni = 0; ni < 4; ++ni)
          acc[mi][ni] = __builtin_amdgcn_mfma_f32_16x16x32_bf16(af[mi], bfr[ni], acc[mi][ni], 0, 0, 0);
    }
  };

  const int NK = 16;
  stage64(Ab, K, As[0], wave, lane, 0);
  stage64(Bb, K, Bs[0], wave, lane, 0);
  __syncthreads();
  for (int it = 0; it < NK; it += 2) {
    stage64(Ab, K, As[1], wave, lane, (it + 1) << 6);
    stage64(Bb, K, Bs[1], wave, lane, (it + 1) << 6);
    compute(As[0], Bs[0]);
    __syncthreads();
    if (it + 2 < NK) {
      stage64(Ab, K, As[0], wave, lane, (it + 2) << 6);
      stage64(Bb, K, Bs[0], wave, lane, (it + 2) << 6);
    }
    compute(As[1], Bs[1]);
    __syncthreads();
  }
#pragma unroll
  for (int mi = 0; mi < 4; ++mi) {
#pragma unroll
    for (int ni = 0; ni < 4; ++ni) {
#pragma unroll
      for (int j = 0; j < 4; ++j) {
        int row = bm + wr + mi * 16 + lhi * 4 + j;
        int col = bnl + wc + ni * 16 + lr;
        unsigned short o = bf_us(acc[mi][ni][j]);
        if (mode == 0) qb[(size_t)row * 512 + col] = o;
        else if (mode == 1) kb[(size_t)row * 512 + col] = o;
        else vTb[(size_t)col * S_LEN + row] = o;
      }
    }
  }
}

// ---------------- gate pre-activations (inline rmsnorm from f32 x) ----------------
__global__ __launch_bounds__(256) void gates_kernel(
    const float* __restrict__ x, const float* __restrict__ n1,
    const float* __restrict__ Wi, const float* __restrict__ bi,
    const float* __restrict__ Wf, const float* __restrict__ bfv,
    float* __restrict__ ipre, float* __restrict__ fpre) {
  int s = blockIdx.x;
  int head = threadIdx.x >> 6, lane = threadIdx.x & 63;
  const float* xr = x + (size_t)s * DMODEL;
  float xv[16];
  float ss = 0.f;
#pragma unroll
  for (int j = 0; j < 16; ++j) { xv[j] = xr[lane + j * 64]; ss += xv[j] * xv[j]; }
#pragma unroll
  for (int off = 32; off > 0; off >>= 1) ss += __shfl_xor(ss, off);
  float scale = rsqrtf(ss * (1.0f / DMODEL) + 1e-6f);
  const float* wi = Wi + head * DMODEL;
  const float* wf = Wf + head * DMODEL;
  float si = 0.f, sf = 0.f;
#pragma unroll
  for (int j = 0; j < 16; ++j) {
    int c = lane + j * 64;
    float xm = xv[j] * scale * n1[c];
    si += xm * wi[c];
    sf += xm * wf[c];
  }
#pragma unroll
  for (int off = 32; off > 0; off >>= 1) {
    si += __shfl_down(si, off);
    sf += __shfl_down(sf, off);
  }
  if (lane == 0) {
    ipre[head * S_LEN + s] = 15.0f * tanhf((si + bi[head]) * (1.0f / 15.0f));
    fpre[head * S_LEN + s] = 15.0f * tanhf((sf + bfv[head]) * (1.0f / 15.0f));
  }
}

// ---------------- per-head scan ----------------
__global__ __launch_bounds__(256) void scan_kernel(
    const float* __restrict__ ipre, const float* __restrict__ fpre,
    float* __restrict__ garr, float* __restrict__ Marr, float* __restrict__ earr) {
  const int h = threadIdx.x >> 6;
  const int lane = threadIdx.x & 63;
  const int base = h * S_LEN + lane * 32;
  float lf[32];
  float lsum = 0.f;
#pragma unroll
  for (int e = 0; e < 32; ++e) {
    float f = fpre[base + e];
    float v = fminf(f, 0.f) - log1pf(expf(-fabsf(f)));
    lf[e] = v;
    lsum += v;
  }
  float scan = lsum;
#pragma unroll
  for (int off = 1; off < 64; off <<= 1) {
    float t = __shfl_up(scan, off);
    if (lane >= off) scan += t;
  }
  float F0 = scan - lsum;
  float gv[32];
  float F = F0, lmax = -1e30f;
#pragma unroll
  for (int e = 0; e < 32; ++e) {
    F += lf[e];
    float g = ipre[base + e] - F;
    gv[e] = g;
    lmax = fmaxf(lmax, g);
    garr[base + e] = g;
  }
  float ms = lmax;
#pragma unroll
  for (int off = 1; off < 64; off <<= 1) {
    float t = __shfl_up(ms, off);
    if (lane >= off) ms = fmaxf(ms, t);
  }
  float em = __shfl_up(ms, 1);
  if (lane == 0) em = -1e30f;
  float run = em;
  F = F0;
#pragma unroll
  for (int e = 0; e < 32; ++e) {
    F += lf[e];
    run = fmaxf(run, gv[e]);
    Marr[base + e] = run;
    earr[base + e] = expf(-(F + run));
  }
}

// ---------------- mLSTM parallel, bf16 MFMA flash-style ----------------
__global__ __launch_bounds__(256) void mlstm_mfma_kernel(
    const unsigned short* __restrict__ Q, const unsigned short* __restrict__ Kb,
    const unsigned short* __restrict__ vT, const float* __restrict__ garr,
    const float* __restrict__ Marr, const float* __restrict__ earr,
    float* __restrict__ hout) {
  const int h = blockIdx.y;
  const int T = blockIdx.x;
  const int tid = threadIdx.x;
  const int w = tid >> 6, l = tid & 63;
  const int lr = l & 15, lg = l >> 4;
  const int hbase = h * S_LEN;
  const int sr = tid >> 4;
  const int sc = tid & 15;

  __shared__ __align__(16) unsigned short Ks[64 * 128];
  __shared__ __align__(16) unsigned short Vs[256 * 64];
  __shared__ __align__(16) unsigned short Ps[64 * 64];

  bf16x8 qf[4];
  {
    const unsigned short* qrow = Q + (size_t)(T * 64 + w * 16 + lr) * 512 + h * 128 + lg * 8;
#pragma unroll
    for (int kt = 0; kt < 4; ++kt) {
      cvu c;
      c.u = *(const u16x8*)(qrow + kt * 32);
      qf[kt] = c.b;
    }
  }
  float Mt[4];
#pragma unroll
  for (int j = 0; j < 4; ++j) Mt[j] = Marr[hbase + T * 64 + w * 16 + lg * 4 + j];

  f32x4v pv[16] = {};
  float nacc[4] = {0.f, 0.f, 0.f, 0.f};
  const float rs = 0.08838834764831845f;  // 1/sqrt(128)

  for (int ch = 0; ch <= T; ++ch) {
    const int s0 = ch * 64;
    __syncthreads();
#pragma unroll
    for (int i = 0; i < 4; ++i) {
      int r = i * 16 + sr;
      u16x8 u = *(const u16x8*)(Kb + (size_t)(s0 + r) * 512 + h * 128 + sc * 8);
      int byte = r * 256 + ((sc * 16) ^ ((r & 7) << 4));
      *(u16x8*)((char*)Ks + byte) = u;
    }
#pragma unroll
    for (int i = 0; i < 16; ++i) {
      int r = i * 16 + sr;
      u16x4 u = *(const u16x4*)(vT + (size_t)(h * 256 + r) * S_LEN + s0 + sc * 4);
      int byte = r * 128 + ((sc * 8) ^ ((r & 7) << 4));
      *(u16x4*)((char*)Vs + byte) = u;
    }
    __syncthreads();
    f32x4v sa[4] = {};
#pragma unroll
    for (int ni = 0; ni < 4; ++ni) {
#pragma unroll
      for (int kt = 0; kt < 4; ++kt) {
        int row = ni * 16 + lr;
        int byte = row * 256 + (((kt * 32 + lg * 8) * 2) ^ ((row & 7) << 4));
        bf16x8 kf = ld_bf8(Ks, byte);
        sa[ni] = __builtin_amdgcn_mfma_f32_16x16x32_bf16(qf[kt], kf, sa[ni], 0, 0, 0);
      }
    }
#pragma unroll
    for (int ni = 0; ni < 4; ++ni) {
      int sl = ni * 16 + lr;
      int sg = s0 + sl;
      float gv = garr[hbase + sg];
#pragma unroll
      for (int j = 0; j < 4; ++j) {
        int tloc = w * 16 + lg * 4 + j;
        int tg = T * 64 + tloc;
        float wgt = (sg <= tg) ? __expf(gv - Mt[j]) : 0.f;
        float val = sa[ni][j] * rs * wgt;
        nacc[j] += val;
        int byte = tloc * 128 + ((sl * 2) ^ ((tloc & 7) << 4));
        *(unsigned short*)((char*)Ps + byte) = bf_us(val);
      }
    }
#pragma unroll
    for (int kt2 = 0; kt2 < 2; ++kt2) {
      int tloc = w * 16 + lr;
      int sb = (kt2 * 32 + lg * 8) * 2;
      bf16x8 pa = ld_bf8(Ps, tloc * 128 + (sb ^ ((tloc & 7) << 4)));
#pragma unroll
      for (int nv = 0; nv < 16; ++nv) {
        int dv = nv * 16 + lr;
        bf16x8 vb = ld_bf8(Vs, dv * 128 + (sb ^ ((dv & 7) << 4)));
        pv[nv] = __builtin_amdgcn_mfma_f32_16x16x32_bf16(pa, vb, pv[nv], 0, 0, 0);
      }
    }
  }
#pragma unroll
  for (int j = 0; j < 4; ++j) {
#pragma unroll
    for (int off = 1; off < 16; off <<= 1) nacc[j] += __shfl_xor(nacc[j], off);
  }
#pragma unroll
  for (int j = 0; j < 4; ++j) {
    int tg = T * 64 + w * 16 + lg * 4 + j;
    float nv = fmaxf(fabsf(nacc[j]), earr[hbase + tg]);
    float inv = 1.0f / (nv + 1e-6f);
    float* orow = hout + (size_t)tg * DMODEL + h * 256;
#pragma unroll
    for (int nvt = 0; nvt < 16; ++nvt) orow[nvt * 16 + lr] = pv[nvt][j] * inv;
  }
}

// ---------------- multihead LayerNorm (DH=256) * mhw -> bf16 ----------------
__global__ __launch_bounds__(256) void mhln_kernel(
    const float* __restrict__ hout, const float* __restrict__ mhw,
    unsigned short* __restrict__ hnb) {
  int s = blockIdx.x;
  int head = threadIdx.x >> 6, lane = threadIdx.x & 63;
  const float* hr = hout + (size_t)s * DMODEL + head * 256;
  float v0 = hr[lane], v1 = hr[lane + 64], v2 = hr[lane + 128], v3 = hr[lane + 192];
  float sum = v0 + v1 + v2 + v3;
#pragma unroll
  for (int off = 32; off > 0; off >>= 1) sum += __shfl_xor(sum, off);
  float mu = sum * (1.0f / 256.0f);
  float d0 = v0 - mu, d1 = v1 - mu, d2 = v2 - mu, d3 = v3 - mu;
  float vs = d0 * d0 + d1 * d1 + d2 * d2 + d3 * d3;
#pragma unroll
  for (int off = 32; off > 0; off >>= 1) vs += __shfl_xor(vs, off);
  float rstd = rsqrtf(vs * (1.0f / 256.0f) + 1e-6f);
  float dn[4] = {d0, d1, d2, d3};
#pragma unroll
  for (int qy = 0; qy < 4; ++qy) {
    int c = head * 256 + qy * 64 + lane;
    hnb[(size_t)s * DMODEL + c] = bf_us(dn[qy] * rstd * mhw[c]);
  }
}

extern "C" void kernel_launch(void* const* d_in, const int* in_sizes, int n_in,
                              void* d_out, int out_size, void* d_ws, size_t ws_size,
                              hipStream_t stream) {
  (void)in_sizes; (void)n_in; (void)out_size; (void)ws_size;
  const int*   tok   = (const int*)d_in[0];
  const float* emb   = (const float*)d_in[1];
  const float* norm1 = (const float*)d_in[2];
  const float* Wq    = (const float*)d_in[3];
  const float* Wk    = (const float*)d_in[4];
  const float* Wv    = (const float*)d_in[5];
  const float* Wog   = (const float*)d_in[6];
  const float* Wi    = (const float*)d_in[7];
  const float* bi    = (const float*)d_in[8];
  const float* Wf    = (const float*)d_in[9];
  const float* bfp   = (const float*)d_in[10];
  const float* mhw   = (const float*)d_in[11];
  const float* Wout  = (const float*)d_in[12];
  const float* norm2 = (const float*)d_in[13];
  const float* Wg    = (const float*)d_in[14];
  const float* Wu    = (const float*)d_in[15];
  const float* Wd    = (const float*)d_in[16];
  const float* onw   = (const float*)d_in[17];
  const float* Wlm   = (const float*)d_in[18];

  char* wsb = (char*)d_ws;
  const size_t MB = 1ull << 20;
  float*          x    = (float*)wsb;                          // 8 MiB
  unsigned short* xmb  = (unsigned short*)(wsb + 8 * MB);      // 4 MiB
  float*          ipre = (float*)(wsb + 12 * MB);              // 5 x 32 KiB
  float*          fpre = ipre + 8192;
  float*          garr = fpre + 8192;
  float*          Marr = garr + 8192;
  float*          earr = Marr + 8192;
  unsigned short* W16  = (unsigned short*)(wsb + 13 * MB);     // 24.5 MiB -> ends 37.5
  const size_t OQ = 0, OKk = 524288, OV = 1048576, OOG = 2097152, OOUT = 3145728,
               OGt = 4194304, OU = 7077888, OD = 9961472;
  unsigned short* qb    = (unsigned short*)(wsb + 38 * MB);    // 2 MiB
  unsigned short* kb    = (unsigned short*)(wsb + 40 * MB);    // 2 MiB
  unsigned short* vTb   = (unsigned short*)(wsb + 42 * MB);    // 4 MiB
  float*          hout  = (float*)(wsb + 46 * MB);             // 8 MiB
  unsigned short* hnb   = (unsigned short*)(wsb + 54 * MB);    // 4 MiB
  unsigned short* gact  = (unsigned short*)(wsb + 58 * MB);    // 4 MiB
  float*          Gf    = (float*)(wsb + 62 * MB);             // 22 MiB -> ends 84
  unsigned short* Gb16  = (unsigned short*)(wsb + 86 * MB);    // 11 MiB -> ends 97
  unsigned short* wlm16 = (unsigned short*)(wsb + 100 * MB);   // 62.5 MiB -> ends 162.5

  embed_kernel<<<2048, 256, 0, stream>>>(tok, emb, x);

  for (int l = 0; l < 2; ++l) {
    const float* n1   = norm1 + (size_t)l * 1024;
    const float* wqv  = Wq   + (size_t)l * 512 * 1024;
    const float* wkv  = Wk   + (size_t)l * 512 * 1024;
    const float* wvv  = Wv   + (size_t)l * 1024 * 1024;
    const float* wogv = Wog  + (size_t)l * 1024 * 1024;
    const float* wiv  = Wi   + (size_t)l * 4 * 1024;
    const float* bil  = bi   + (size_t)l * 4;
    const float* wfv  = Wf   + (size_t)l * 4 * 1024;
    const float* bfl  = bfp  + (size_t)l * 4;
    const float* mhwl = mhw  + (size_t)l * 1024;
    const float* wov  = Wout + (size_t)l * 1024 * 1024;
    const float* n2   = norm2 + (size_t)l * 1024;
    const float* wgv  = Wg   + (size_t)l * 2752 * 1024;
    const float* wuv  = Wu   + (size_t)l * 2752 * 1024;
    const float* wdv  = Wd   + (size_t)l * 1024 * 2752;

    rmsnorm_kernel<<<2048, 256, 0, stream>>>(x, n1, xmb);
    wcvt8_kernel<<<6272, 256, 0, stream>>>(wqv, wkv, wvv, wogv, wov, wgv, wuv, wdv, W16);
    qkv_kernel<<<dim3(16, 16), 256, 0, stream>>>(xmb, W16 + OQ, W16 + OKk, W16 + OV,
                                                 qb, kb, vTb);
    gates_kernel<<<2048, 256, 0, stream>>>(x, n1, wiv, bil, wfv, bfl, ipre, fpre);
    scan_kernel<<<1, 256, 0, stream>>>(ipre, fpre, garr, Marr, earr);
    mlstm_mfma_kernel<<<dim3(32, 4), 256, 0, stream>>>(qb, kb, vTb, garr, Marr, earr, hout);
    mhln_kernel<<<2048, 256, 0, stream>>>(hout, mhwl, hnb);
    gemm_bb_kernel<5><<<dim3(16, 8), 256, 0, stream>>>(xmb, W16 + OOG, hnb, gact, 1024, 1024);
    gemm_bb_kernel<1><<<dim3(16, 8), 256, 0, stream>>>(gact, W16 + OOUT, x, x, 1024, 1024);
    rmsnorm_kernel<<<2048, 256, 0, stream>>>(x, n2, xmb);
    gemm_bb_kernel<0><<<dim3(16, 22), 256, 0, stream>>>(xmb, W16 + OGt, nullptr, Gf, 1024, 2816);
    gemm_bb_kernel<6><<<dim3(16, 22), 256, 0, stream>>>(xmb, W16 + OU, Gf, Gb16, 1024, 2816);
    gemm_bb_kernel<1><<<dim3(16, 8), 256, 0, stream>>>(Gb16, W16 + OD, x, x, 2816, 1024);
  }

  rmsnorm_kernel<<<2048, 256, 0, stream>>>(x, onw, xmb);
  cvt_kernel<<<16000, 256, 0, stream>>>(Wlm, wlm16);
  gemm_bb_kernel<2><<<dim3(16, 250), 256, 0, stream>>>(
      xmb, wlm16, nullptr, (float*)d_out, 1024, 32000);
}